// Round 1
// baseline (1628.575 us; speedup 1.0000x reference)
//
#include <hip/hip_runtime.h>
#include <math.h>

// Problem constants (B=32, C=32, H=W=32, V=4096)
#define BS    32
#define CH    32
#define HH    32
#define VV    4096
#define FELEMS (BS*CH*HH*HH)   // 1048576

// ---------------------------------------------------------------------------
// e_sq[v] = sum_c emb[v,c]^2
__global__ __launch_bounds__(256) void esq_kernel(const float* __restrict__ emb,
                                                  float* __restrict__ esq) {
    int v = blockIdx.x * 256 + threadIdx.x;
    const float4* e4 = (const float4*)(emb + (size_t)v * CH);
    float s = 0.f;
#pragma unroll
    for (int i = 0; i < 8; i++) {
        float4 e = e4[i];
        s += e.x*e.x + e.y*e.y + e.z*e.z + e.w*e.w;
    }
    esq[v] = s;
}

// ---------------------------------------------------------------------------
// sum of squares of f -> atomicAdd into acc (acc pre-zeroed)
__global__ __launch_bounds__(256) void sumsq_kernel(const float* __restrict__ f,
                                                    float* __restrict__ acc, int n) {
    __shared__ float sh[256];
    float s = 0.f;
    for (int i = blockIdx.x * 256 + threadIdx.x; i < n; i += gridDim.x * 256) {
        float v = f[i];
        s = fmaf(v, v, s);
    }
    sh[threadIdx.x] = s;
    __syncthreads();
    for (int o = 128; o > 0; o >>= 1) {
        if (threadIdx.x < o) sh[threadIdx.x] += sh[threadIdx.x + o];
        __syncthreads();
    }
    if (threadIdx.x == 0) atomicAdd(acc, sh[0]);
}

// ---------------------------------------------------------------------------
// mean-pool f_rest (B,C,32,32) -> z[N,C], N = B*pn*pn, row n=(b*pn+i)*pn+j
__global__ __launch_bounds__(256) void pool_kernel(const float* __restrict__ f,
                                                   float* __restrict__ z, int pn) {
    int tid = blockIdx.x * 256 + threadIdx.x;
    int c = tid % CH;
    int n = tid / CH;
    int nrows = BS * pn * pn;
    if (n >= nrows) return;
    int j = n % pn, i = (n / pn) % pn, b = n / (pn * pn);
    int ps = HH / pn;
    const float* base = f + (((size_t)(b * CH + c) * HH) + i * ps) * HH + j * ps;
    float s = 0.f;
    for (int dy = 0; dy < ps; dy++)
        for (int dx = 0; dx < ps; dx++)
            s += base[dy * HH + dx];
    z[(size_t)n * CH + c] = s * (1.0f / (ps * ps));
}

// ---------------------------------------------------------------------------
// Nearest-code argmin. R threads per row (contiguous code chunks of 4096/R),
// G=256/R rows per block. For R<=4 the chunk id r=tid/G is wave-uniform so
// emb loads coalesce to one L1 line per float4.
template <int R>
__global__ __launch_bounds__(256) void argmin_kernel(const float* __restrict__ z,
                                                     const float* __restrict__ emb,
                                                     const float* __restrict__ esq,
                                                     int* __restrict__ out_idx,
                                                     float* __restrict__ hits) {
    constexpr int G = 256 / R;    // rows per block
    constexpr int K = VV / R;     // codes per thread
    const int row_local = threadIdx.x % G;
    const int r = threadIdx.x / G;
    const int n = blockIdx.x * G + row_local;

    float zr[CH];
    {
        const float4* zp = (const float4*)(z + (size_t)n * CH);
#pragma unroll
        for (int i = 0; i < 8; i++) {
            float4 t = zp[i];
            zr[4*i+0] = t.x; zr[4*i+1] = t.y; zr[4*i+2] = t.z; zr[4*i+3] = t.w;
        }
    }

    float best = 3.402823466e38f;
    int bi = 0;
    const int v0 = r * K;
    for (int vv = 0; vv < K; vv += 2) {
#pragma unroll
        for (int u = 0; u < 2; u++) {
            int v = v0 + vv + u;
            const float4* e4 = (const float4*)(emb + (size_t)v * CH);
            float a0 = 0.f, a1 = 0.f, a2 = 0.f, a3 = 0.f;
#pragma unroll
            for (int i = 0; i < 8; i++) {
                float4 e = e4[i];
                a0 = fmaf(zr[4*i+0], e.x, a0);
                a1 = fmaf(zr[4*i+1], e.y, a1);
                a2 = fmaf(zr[4*i+2], e.z, a2);
                a3 = fmaf(zr[4*i+3], e.w, a3);
            }
            float d = esq[v] - 2.0f * ((a0 + a1) + (a2 + a3));
            if (d < best) { best = d; bi = v; }   // strict < keeps first (lowest v)
        }
    }

    __shared__ float sbest[256];
    __shared__ int   sidx[256];
    sbest[threadIdx.x] = best;
    sidx[threadIdx.x]  = bi;
    __syncthreads();
    if (r == 0) {
        // chunks visited in increasing-index order; strict < keeps earliest on ties
        for (int rr = 1; rr < R; rr++) {
            float d2 = sbest[rr * G + row_local];
            if (d2 < best) { best = d2; bi = sidx[rr * G + row_local]; }
        }
        out_idx[n] = bi;
        atomicAdd(&hits[bi], 1.0f);
    }
}

// ---------------------------------------------------------------------------
// h_small[b,c,i,j] = emb[idx[(b*pn+i)*pn+j], c]
__global__ __launch_bounds__(256) void gather_kernel(const int* __restrict__ idx,
                                                     const float* __restrict__ emb,
                                                     float* __restrict__ hs, int pn) {
    int tid = blockIdx.x * 256 + threadIdx.x;
    int tot = BS * CH * pn * pn;
    if (tid >= tot) return;
    int j = tid % pn;
    int i = (tid / pn) % pn;
    int c = (tid / (pn * pn)) % CH;
    int b = tid / (pn * pn * CH);
    int n = (b * pn + i) * pn + j;
    hs[tid] = emb[(size_t)idx[n] * CH + c];
}

// ---------------------------------------------------------------------------
// bicubic weights, a=-0.75, half-pixel, edge clamp (matches torch/ref _bicubic_mat)
__device__ inline void cubic_w(float xs, int pn, int* ix, float* w) {
    const float a = -0.75f;
    float xf = floorf(xs);
    int x0 = (int)xf;
    float t = xs - xf;
#pragma unroll
    for (int j = -1; j <= 2; j++) {
        float d = fabsf(t - (float)j);
        float ww;
        if (d < 1.0f)      ww = ((a + 2.0f) * d - (a + 3.0f)) * d * d + 1.0f;
        else if (d < 2.0f) ww = ((a * d - 5.0f * a) * d + 8.0f * a) * d - 4.0f * a;
        else               ww = 0.0f;
        int xi = x0 + j;
        xi = xi < 0 ? 0 : (xi > pn - 1 ? pn - 1 : xi);
        ix[j + 1] = xi;
        w[j + 1]  = ww;
    }
}

// h_up[b,c,Y,X] = sum_{a,b2} wy[a]*wx[b2]*hs[b,c,iy[a],ix[b2]]
__global__ __launch_bounds__(256) void upsample_kernel(const float* __restrict__ hs,
                                                       float* __restrict__ hu, int pn) {
    int tid = blockIdx.x * 256 + threadIdx.x;   // B*C*32*32 threads
    int X = tid % HH;
    int Y = (tid / HH) % HH;
    int bc = tid / (HH * HH);
    float scale = (float)pn / (float)HH;
    int iy[4], ix[4];
    float wy[4], wx[4];
    cubic_w(((float)Y + 0.5f) * scale - 0.5f, pn, iy, wy);
    cubic_w(((float)X + 0.5f) * scale - 0.5f, pn, ix, wx);
    const float* base = hs + (size_t)bc * pn * pn;
    float s = 0.f;
#pragma unroll
    for (int a = 0; a < 4; a++) {
        float rsum = 0.f;
#pragma unroll
        for (int b2 = 0; b2 < 4; b2++)
            rsum = fmaf(base[iy[a] * pn + ix[b2]], wx[b2], rsum);
        s = fmaf(rsum, wy[a], s);
    }
    hu[tid] = s;
}

// ---------------------------------------------------------------------------
// Phi + residual update: f_rest -= 0.5*h + 0.5*(conv3x3(h)+bias)
// block: 256 threads = 8 rows x 32 cols; grid = B*C*4
__global__ __launch_bounds__(256) void conv_phi_kernel(const float* __restrict__ hin,
                                                       const float* __restrict__ w,
                                                       const float* __restrict__ bias,
                                                       float* __restrict__ frest) {
    int tid = threadIdx.x;
    int x  = tid % HH;
    int yl = tid / HH;                  // 0..7
    int yt = blockIdx.x % 4;
    int co = (blockIdx.x / 4) % CH;
    int b  = blockIdx.x / (4 * CH);
    int y  = yt * 8 + yl;

    float acc = bias[co];
    const float* wbase = w + (size_t)co * CH * 9;
    for (int ci = 0; ci < CH; ci++) {
        const float* hp = hin + ((size_t)(b * CH + ci) * HH) * HH;
        const float* wp = wbase + ci * 9;
#pragma unroll
        for (int ky = 0; ky < 3; ky++) {
            int iy = y + ky - 1;
            if (iy < 0 || iy > HH - 1) continue;
#pragma unroll
            for (int kx = 0; kx < 3; kx++) {
                int ix = x + kx - 1;
                if (ix < 0 || ix > HH - 1) continue;
                acc = fmaf(hp[iy * HH + ix], wp[ky * 3 + kx], acc);
            }
        }
    }
    size_t off = ((size_t)(b * CH + co) * HH + y) * HH + x;
    float hc = hin[off];
    frest[off] -= 0.5f * hc + 0.5f * acc;   // RESI = 0.5
}

// ---------------------------------------------------------------------------
// perplexity + loss finalize (single block)
__global__ __launch_bounds__(256) void finalize_kernel(const float* __restrict__ hits,
                                                       const float* __restrict__ lacc,
                                                       float* __restrict__ outs) {
    __shared__ float sh[256];
    int t = threadIdx.x;
    float s = 0.f;
    for (int v = t; v < VV; v += 256) s += hits[v];
    sh[t] = s;
    __syncthreads();
    for (int o = 128; o > 0; o >>= 1) {
        if (t < o) sh[t] += sh[t + o];
        __syncthreads();
    }
    float total = sh[0];
    __syncthreads();
    float tot = fmaxf(total, 1.0f);
    float ent = 0.f;
    for (int v = t; v < VV; v += 256) {
        float p = hits[v] / tot;
        ent += p * logf(p + 1e-10f);
    }
    sh[t] = ent;
    __syncthreads();
    for (int o = 128; o > 0; o >>= 1) {
        if (t < o) sh[t] += sh[t + o];
        __syncthreads();
    }
    if (t == 0) {
        // loss = SN*(1+BETA)*mean(f^2) = 7.5 * sumsq / 1048576  (f_hat stays 0)
        outs[0] = 7.5f * lacc[0] * (1.0f / (float)FELEMS);
        outs[1] = expf(-sh[0]);
    }
}

// ---------------------------------------------------------------------------
extern "C" void kernel_launch(void* const* d_in, const int* in_sizes, int n_in,
                              void* d_out, int out_size, void* d_ws, size_t ws_size,
                              hipStream_t stream) {
    const float* f   = (const float*)d_in[0];   // (32,32,32,32)
    const float* emb = (const float*)d_in[1];   // (4096,32)
    const float* phw = (const float*)d_in[2];   // (4,32,32,3,3)
    const float* phb = (const float*)d_in[3];   // (4,32)
    float* out = (float*)d_out;                 // f_hat (1048576) + loss + perplexity

    float* ws    = (float*)d_ws;
    float* hits  = ws;                          // 4096
    float* esq   = ws + 4096;                   // 4096
    float* lacc  = ws + 8192;                   // 1 (+pad to 8448)
    int*   idxb  = (int*)(ws + 8448);           // 32768 ints
    float* frest = ws + 8448 + 32768;           // 1048576
    float* zbuf  = frest + FELEMS;              // 1048576 (z, then h_small)
    float* hup   = zbuf + FELEMS;               // 1048576

    // f_hat output is exactly zero; scalars overwritten by finalize
    hipMemsetAsync(d_out, 0, (size_t)out_size * sizeof(float), stream);
    // zero hits + esq + lacc region
    hipMemsetAsync(ws, 0, (size_t)8448 * sizeof(float), stream);
    hipMemcpyAsync(frest, f, (size_t)FELEMS * sizeof(float),
                   hipMemcpyDeviceToDevice, stream);

    esq_kernel<<<VV / 256, 256, 0, stream>>>(emb, esq);
    sumsq_kernel<<<256, 256, 0, stream>>>(f, lacc, FELEMS);

    const int pns[6] = {1, 2, 4, 8, 16, 32};
    const int sel[6] = {0, 0, 1, 2, 3, 3};   // PHI_SEL

    for (int si = 0; si < 6; si++) {
        int pn = pns[si];
        int N = BS * pn * pn;                 // rows at this scale
        pool_kernel<<<(N * CH + 255) / 256, 256, 0, stream>>>(frest, zbuf, pn);

        if (si == 5)
            argmin_kernel<4><<<N / 64, 256, 0, stream>>>(zbuf, emb, esq, idxb, hits);
        else if (si == 4)
            argmin_kernel<16><<<N / 16, 256, 0, stream>>>(zbuf, emb, esq, idxb, hits);
        else
            argmin_kernel<64><<<N / 4, 256, 0, stream>>>(zbuf, emb, esq, idxb, hits);

        gather_kernel<<<(BS * CH * pn * pn + 255) / 256, 256, 0, stream>>>(idxb, emb, zbuf, pn);

        const float* cin = zbuf;
        if (si != 5) {
            upsample_kernel<<<FELEMS / 256, 256, 0, stream>>>(zbuf, hup, pn);
            cin = hup;
        }
        conv_phi_kernel<<<BS * CH * 4, 256, 0, stream>>>(
            cin, phw + (size_t)sel[si] * CH * CH * 9, phb + (size_t)sel[si] * CH, frest);
    }

    finalize_kernel<<<1, 256, 0, stream>>>(hits, lacc, out + (out_size - 2));
}

// Round 2
// 1594.061 us; speedup vs baseline: 1.0217x; 1.0217x over previous
//
#include <hip/hip_runtime.h>
#include <math.h>
#include <float.h>

// Problem constants (B=32, C=32, H=W=32, V=4096)
#define BS    32
#define CH    32
#define HH    32
#define VV    4096
#define FELEMS (BS*CH*HH*HH)   // 1048576

// ---------------------------------------------------------------------------
// esqh[v] = 0.5 * sum_c emb[v,c]^2   (score form: argmin d == argmax dot-esqh)
__global__ __launch_bounds__(256) void esq_kernel(const float* __restrict__ emb,
                                                  float* __restrict__ esqh) {
    int v = blockIdx.x * 256 + threadIdx.x;
    const float4* e4 = (const float4*)(emb + (size_t)v * CH);
    float s = 0.f;
#pragma unroll
    for (int i = 0; i < 8; i++) {
        float4 e = e4[i];
        s += e.x*e.x + e.y*e.y + e.z*e.z + e.w*e.w;
    }
    esqh[v] = 0.5f * s;
}

// ---------------------------------------------------------------------------
// sum of squares of f -> atomicAdd into acc (acc pre-zeroed)
__global__ __launch_bounds__(256) void sumsq_kernel(const float* __restrict__ f,
                                                    float* __restrict__ acc, int n) {
    __shared__ float sh[256];
    float s = 0.f;
    for (int i = blockIdx.x * 256 + threadIdx.x; i < n; i += gridDim.x * 256) {
        float v = f[i];
        s = fmaf(v, v, s);
    }
    sh[threadIdx.x] = s;
    __syncthreads();
    for (int o = 128; o > 0; o >>= 1) {
        if (threadIdx.x < o) sh[threadIdx.x] += sh[threadIdx.x + o];
        __syncthreads();
    }
    if (threadIdx.x == 0) atomicAdd(acc, sh[0]);
}

// ---------------------------------------------------------------------------
// mean-pool f_rest (B,C,32,32) -> z[N,C], N = B*pn*pn, row n=(b*pn+i)*pn+j
__global__ __launch_bounds__(256) void pool_kernel(const float* __restrict__ f,
                                                   float* __restrict__ z, int pn) {
    int tid = blockIdx.x * 256 + threadIdx.x;
    int c = tid % CH;
    int n = tid / CH;
    int nrows = BS * pn * pn;
    if (n >= nrows) return;
    int j = n % pn, i = (n / pn) % pn, b = n / (pn * pn);
    int ps = HH / pn;
    const float* base = f + (((size_t)(b * CH + c) * HH) + i * ps) * HH + j * ps;
    float s = 0.f;
    for (int dy = 0; dy < ps; dy++)
        for (int dx = 0; dx < ps; dx++)
            s += base[dy * HH + dx];
    z[(size_t)n * CH + c] = s * (1.0f / (ps * ps));
}

// ---------------------------------------------------------------------------
// Nearest-code argmax of (z.e - 0.5*|e|^2).
// R chunks of codes per row-group; each thread handles T rows (emb reuse).
// G=256/R row-groups per block; rows per block = G*T.
// r = tid/G is wave-uniform (or near-uniform) so emb loads broadcast.
template <int R, int T>
__global__ __launch_bounds__(256) void argmin_kernel(const float* __restrict__ z,
                                                     const float* __restrict__ emb,
                                                     const float* __restrict__ esqh,
                                                     int* __restrict__ out_idx,
                                                     float* __restrict__ hits) {
    constexpr int G = 256 / R;    // row-groups per block
    constexpr int K = VV / R;     // codes per thread
    const int g = threadIdx.x % G;
    const int r = threadIdx.x / G;
    const int row0 = (blockIdx.x * G + g) * T;

    float zr[T][CH];
#pragma unroll
    for (int t = 0; t < T; t++) {
        const float4* zp = (const float4*)(z + (size_t)(row0 + t) * CH);
#pragma unroll
        for (int i = 0; i < 8; i++) {
            float4 q = zp[i];
            zr[t][4*i+0] = q.x; zr[t][4*i+1] = q.y;
            zr[t][4*i+2] = q.z; zr[t][4*i+3] = q.w;
        }
    }

    float best[T];
    int   bi[T];
#pragma unroll
    for (int t = 0; t < T; t++) { best[t] = -FLT_MAX; bi[t] = 0; }

    const int v0 = r * K;
    for (int vv = 0; vv < K; vv++) {
        const int v = v0 + vv;
        float e[CH];
        {
            const float4* e4 = (const float4*)(emb + (size_t)v * CH);
#pragma unroll
            for (int i = 0; i < 8; i++) {
                float4 q = e4[i];
                e[4*i+0] = q.x; e[4*i+1] = q.y; e[4*i+2] = q.z; e[4*i+3] = q.w;
            }
        }
        const float eh = esqh[v];
#pragma unroll
        for (int t = 0; t < T; t++) {
            float a0 = 0.f, a1 = 0.f;
#pragma unroll
            for (int i = 0; i < 16; i++) {
                a0 = fmaf(zr[t][2*i+0], e[2*i+0], a0);
                a1 = fmaf(zr[t][2*i+1], e[2*i+1], a1);
            }
            float s = (a0 + a1) - eh;
            if (s > best[t]) { best[t] = s; bi[t] = v; }  // strict >: lowest v on tie
        }
    }

    __shared__ float sb[T * 256];
    __shared__ int   si_[T * 256];
#pragma unroll
    for (int t = 0; t < T; t++) {
        sb[t * 256 + threadIdx.x]  = best[t];
        si_[t * 256 + threadIdx.x] = bi[t];
    }
    __syncthreads();
    if (r == 0) {   // tid < G
#pragma unroll
        for (int t = 0; t < T; t++) {
            float b = best[t];
            int id = bi[t];
            for (int rr = 1; rr < R; rr++) {   // increasing v: strict > keeps lowest
                float s2 = sb[t * 256 + rr * G + g];
                if (s2 > b) { b = s2; id = si_[t * 256 + rr * G + g]; }
            }
            out_idx[row0 + t] = id;
            atomicAdd(&hits[id], 1.0f);
        }
    }
}

// ---------------------------------------------------------------------------
// h_small[b,c,i,j] = emb[idx[(b*pn+i)*pn+j], c]
__global__ __launch_bounds__(256) void gather_kernel(const int* __restrict__ idx,
                                                     const float* __restrict__ emb,
                                                     float* __restrict__ hs, int pn) {
    int tid = blockIdx.x * 256 + threadIdx.x;
    int tot = BS * CH * pn * pn;
    if (tid >= tot) return;
    int j = tid % pn;
    int i = (tid / pn) % pn;
    int c = (tid / (pn * pn)) % CH;
    int b = tid / (pn * pn * CH);
    int n = (b * pn + i) * pn + j;
    hs[tid] = emb[(size_t)idx[n] * CH + c];
}

// ---------------------------------------------------------------------------
// bicubic weights, a=-0.75, half-pixel, edge clamp (matches torch/ref _bicubic_mat)
__device__ inline void cubic_w(float xs, int pn, int* ix, float* w) {
    const float a = -0.75f;
    float xf = floorf(xs);
    int x0 = (int)xf;
    float t = xs - xf;
#pragma unroll
    for (int j = -1; j <= 2; j++) {
        float d = fabsf(t - (float)j);
        float ww;
        if (d < 1.0f)      ww = ((a + 2.0f) * d - (a + 3.0f)) * d * d + 1.0f;
        else if (d < 2.0f) ww = ((a * d - 5.0f * a) * d + 8.0f * a) * d - 4.0f * a;
        else               ww = 0.0f;
        int xi = x0 + j;
        xi = xi < 0 ? 0 : (xi > pn - 1 ? pn - 1 : xi);
        ix[j + 1] = xi;
        w[j + 1]  = ww;
    }
}

// h_up[b,c,Y,X] = sum_{a,b2} wy[a]*wx[b2]*hs[b,c,iy[a],ix[b2]]
__global__ __launch_bounds__(256) void upsample_kernel(const float* __restrict__ hs,
                                                       float* __restrict__ hu, int pn) {
    int tid = blockIdx.x * 256 + threadIdx.x;   // B*C*32*32 threads
    int X = tid % HH;
    int Y = (tid / HH) % HH;
    int bc = tid / (HH * HH);
    float scale = (float)pn / (float)HH;
    int iy[4], ix[4];
    float wy[4], wx[4];
    cubic_w(((float)Y + 0.5f) * scale - 0.5f, pn, iy, wy);
    cubic_w(((float)X + 0.5f) * scale - 0.5f, pn, ix, wx);
    const float* base = hs + (size_t)bc * pn * pn;
    float s = 0.f;
#pragma unroll
    for (int a = 0; a < 4; a++) {
        float rsum = 0.f;
#pragma unroll
        for (int b2 = 0; b2 < 4; b2++)
            rsum = fmaf(base[iy[a] * pn + ix[b2]], wx[b2], rsum);
        s = fmaf(rsum, wy[a], s);
    }
    hu[tid] = s;
}

// ---------------------------------------------------------------------------
// Phi + residual update: f_rest -= 0.5*h + 0.5*(conv3x3(h)+bias)
// grid: b(32) x yt(4) x co-half(2) = 256 blocks; block 256 = tx(32) x ty(8).
// Thread computes 8 rows x col tx x 2 output channels (co = chh*16 + ty*2 + u).
// LDS: weights for 16 co (padded 9->12 for b128 reads) + zero-padded input tile.
__global__ __launch_bounds__(256) void conv_phi_kernel(const float* __restrict__ hin,
                                                       const float* __restrict__ w,
                                                       const float* __restrict__ bias,
                                                       float* __restrict__ frest) {
    const int chh = blockIdx.x & 1;
    const int yt  = (blockIdx.x >> 1) & 3;
    const int b   = blockIdx.x >> 3;
    const int tx  = threadIdx.x & 31;
    const int ty  = threadIdx.x >> 5;     // 0..7
    const int y0  = yt * 8;

    __shared__ float wl[16 * 32 * 12];    // 24 KB
    __shared__ float til[16 * 10 * 34];   // 21.25 KB

    // stage weights for this co-half: [co16][ci32][9] -> padded [..][12]
    {
        const float* wsrc = w + (size_t)chh * 16 * CH * 9;
        for (int i = threadIdx.x; i < 16 * 32 * 12; i += 256) {
            int k = i % 12;
            wl[i] = (k < 9) ? wsrc[(i / 12) * 9 + k] : 0.f;
        }
    }

    float acc[8][2];
    const int co0 = chh * 16 + ty * 2;
#pragma unroll
    for (int ry = 0; ry < 8; ry++) {
        acc[ry][0] = bias[co0 + 0];
        acc[ry][1] = bias[co0 + 1];
    }

    for (int cc = 0; cc < 2; cc++) {
        __syncthreads();
        // stage input: ci = cc*16 + 0..15, rows y0-1..y0+8, cols -1..32 (zero pad)
        for (int i = threadIdx.x; i < 16 * 10 * 34; i += 256) {
            int col = i % 34;
            int row = (i / 34) % 10;
            int cil = i / 340;
            int gy = y0 - 1 + row;
            int gx = col - 1;
            float vv = 0.f;
            if ((unsigned)gy < 32u && (unsigned)gx < 32u)
                vv = hin[(((size_t)(b * CH + cc * 16 + cil)) * HH + gy) * HH + gx];
            til[i] = vv;
        }
        __syncthreads();

        for (int cil = 0; cil < 16; cil++) {
            float in[10][3];
            const float* tp = &til[cil * 340];
#pragma unroll
            for (int rr2 = 0; rr2 < 10; rr2++)
#pragma unroll
                for (int dx = 0; dx < 3; dx++)
                    in[rr2][dx] = tp[rr2 * 34 + tx + dx];
#pragma unroll
            for (int u = 0; u < 2; u++) {
                const int col = ty * 2 + u;                 // co_local
                const float* wp = &wl[(col * 32 + cc * 16 + cil) * 12];
                float4 wa = *(const float4*)wp;
                float4 wb = *(const float4*)(wp + 4);
                float  w8 = wp[8];
#pragma unroll
                for (int ry = 0; ry < 8; ry++) {
                    float s = acc[ry][u];
                    s = fmaf(in[ry + 0][0], wa.x, s);
                    s = fmaf(in[ry + 0][1], wa.y, s);
                    s = fmaf(in[ry + 0][2], wa.z, s);
                    s = fmaf(in[ry + 1][0], wa.w, s);
                    s = fmaf(in[ry + 1][1], wb.x, s);
                    s = fmaf(in[ry + 1][2], wb.y, s);
                    s = fmaf(in[ry + 2][0], wb.z, s);
                    s = fmaf(in[ry + 2][1], wb.w, s);
                    s = fmaf(in[ry + 2][2], w8,   s);
                    acc[ry][u] = s;
                }
            }
        }
    }

    // f_rest -= 0.5*h + 0.5*(conv+bias)
#pragma unroll
    for (int ry = 0; ry < 8; ry++) {
#pragma unroll
        for (int u = 0; u < 2; u++) {
            int co = co0 + u;
            size_t off = (((size_t)(b * CH + co)) * HH + (y0 + ry)) * HH + tx;
            float hc = hin[off];
            frest[off] -= 0.5f * hc + 0.5f * acc[ry][u];
        }
    }
}

// ---------------------------------------------------------------------------
// perplexity + loss finalize (single block)
__global__ __launch_bounds__(256) void finalize_kernel(const float* __restrict__ hits,
                                                       const float* __restrict__ lacc,
                                                       float* __restrict__ outs) {
    __shared__ float sh[256];
    int t = threadIdx.x;
    float s = 0.f;
    for (int v = t; v < VV; v += 256) s += hits[v];
    sh[t] = s;
    __syncthreads();
    for (int o = 128; o > 0; o >>= 1) {
        if (t < o) sh[t] += sh[t + o];
        __syncthreads();
    }
    float total = sh[0];
    __syncthreads();
    float tot = fmaxf(total, 1.0f);
    float ent = 0.f;
    for (int v = t; v < VV; v += 256) {
        float p = hits[v] / tot;
        ent += p * logf(p + 1e-10f);
    }
    sh[t] = ent;
    __syncthreads();
    for (int o = 128; o > 0; o >>= 1) {
        if (t < o) sh[t] += sh[t + o];
        __syncthreads();
    }
    if (t == 0) {
        // loss = SN*(1+BETA)*mean(f^2) = 7.5 * sumsq / 1048576  (f_hat stays 0)
        outs[0] = 7.5f * lacc[0] * (1.0f / (float)FELEMS);
        outs[1] = expf(-sh[0]);
    }
}

// ---------------------------------------------------------------------------
extern "C" void kernel_launch(void* const* d_in, const int* in_sizes, int n_in,
                              void* d_out, int out_size, void* d_ws, size_t ws_size,
                              hipStream_t stream) {
    const float* f   = (const float*)d_in[0];   // (32,32,32,32)
    const float* emb = (const float*)d_in[1];   // (4096,32)
    const float* phw = (const float*)d_in[2];   // (4,32,32,3,3)
    const float* phb = (const float*)d_in[3];   // (4,32)
    float* out = (float*)d_out;                 // f_hat (1048576) + loss + perplexity

    float* ws    = (float*)d_ws;
    float* hits  = ws;                          // 4096
    float* esqh  = ws + 4096;                   // 4096
    float* lacc  = ws + 8192;                   // 1 (+pad to 8448)
    int*   idxb  = (int*)(ws + 8448);           // 32768 ints
    float* frest = ws + 8448 + 32768;           // 1048576
    float* zbuf  = frest + FELEMS;              // 1048576 (z, then h_small)
    float* hup   = zbuf + FELEMS;               // 1048576

    // f_hat output is exactly zero; scalars overwritten by finalize
    hipMemsetAsync(d_out, 0, (size_t)out_size * sizeof(float), stream);
    // zero hits + esqh + lacc region
    hipMemsetAsync(ws, 0, (size_t)8448 * sizeof(float), stream);
    hipMemcpyAsync(frest, f, (size_t)FELEMS * sizeof(float),
                   hipMemcpyDeviceToDevice, stream);

    esq_kernel<<<VV / 256, 256, 0, stream>>>(emb, esqh);
    sumsq_kernel<<<256, 256, 0, stream>>>(f, lacc, FELEMS);

    const int pns[6] = {1, 2, 4, 8, 16, 32};
    const int sel[6] = {0, 0, 1, 2, 3, 3};   // PHI_SEL

    for (int si = 0; si < 6; si++) {
        int pn = pns[si];
        int N = BS * pn * pn;                 // rows at this scale
        pool_kernel<<<(N * CH + 255) / 256, 256, 0, stream>>>(frest, zbuf, pn);

        if (si == 5)       // N=32768: 512 blocks, FMA:load 8:1, r wave-pair-uniform
            argmin_kernel<8, 2><<<N / 64, 256, 0, stream>>>(zbuf, emb, esqh, idxb, hits);
        else if (si == 4)  // N=8192: 256 blocks
            argmin_kernel<16, 2><<<N / 32, 256, 0, stream>>>(zbuf, emb, esqh, idxb, hits);
        else if (si == 3)  // N=2048: 128 blocks
            argmin_kernel<32, 2><<<N / 16, 256, 0, stream>>>(zbuf, emb, esqh, idxb, hits);
        else               // tiny scales
            argmin_kernel<64, 1><<<N / 4, 256, 0, stream>>>(zbuf, emb, esqh, idxb, hits);

        gather_kernel<<<(BS * CH * pn * pn + 255) / 256, 256, 0, stream>>>(idxb, emb, zbuf, pn);

        const float* cin = zbuf;
        if (si != 5) {
            upsample_kernel<<<FELEMS / 256, 256, 0, stream>>>(zbuf, hup, pn);
            cin = hup;
        }
        conv_phi_kernel<<<BS * CH * 4 * 2 / 4, 256, 0, stream>>>(
            cin, phw + (size_t)sel[si] * CH * CH * 9, phb + (size_t)sel[si] * CH, frest);
    }

    finalize_kernel<<<1, 256, 0, stream>>>(hits, lacc, out + (out_size - 2));
}

// Round 4
// 660.079 us; speedup vs baseline: 2.4672x; 2.4150x over previous
//
#include <hip/hip_runtime.h>
#include <math.h>
#include <float.h>

// Problem constants (B=32, C=32, H=W=32, V=4096)
#define BS    32
#define CH    32
#define HH    32
#define VV    4096
#define FELEMS (BS*CH*HH*HH)   // 1048576

typedef unsigned short ushort_t;
typedef __attribute__((ext_vector_type(8))) short short8;
typedef __attribute__((ext_vector_type(4))) float floatx4;

// RNE round fp32 -> bf16 bits
__device__ inline unsigned bf16_rne(float x) {
    unsigned u = __builtin_bit_cast(unsigned, x);
    return (u + 0x7FFFu + ((u >> 16) & 1u)) >> 16;
}

// 3-way bf16 split: x ~= hi + mid + lo, residual <= 2^-26 |x|
__device__ inline void split3(float x, ushort_t* h, ushort_t* m, ushort_t* l) {
    unsigned hb = bf16_rne(x);
    float r1 = x - __builtin_bit_cast(float, hb << 16);
    unsigned mb = bf16_rne(r1);
    float r2 = r1 - __builtin_bit_cast(float, mb << 16);
    unsigned lb = bf16_rne(r2);
    *h = (ushort_t)hb; *m = (ushort_t)mb; *l = (ushort_t)lb;
}

// ---------------------------------------------------------------------------
// esqh[v] = 0.5 * sum_c emb[v,c]^2   (argmin d == argmax dot - esqh)
__global__ __launch_bounds__(256) void esq_kernel(const float* __restrict__ emb,
                                                  float* __restrict__ esqh) {
    int v = blockIdx.x * 256 + threadIdx.x;
    const float4* e4 = (const float4*)(emb + (size_t)v * CH);
    float s = 0.f;
#pragma unroll
    for (int i = 0; i < 8; i++) {
        float4 e = e4[i];
        s += e.x*e.x + e.y*e.y + e.z*e.z + e.w*e.w;
    }
    esqh[v] = 0.5f * s;
}

// ---------------------------------------------------------------------------
// split emb into bf16 hi/mid/lo (131072 elems)
__global__ __launch_bounds__(256) void embsplit_kernel(const float* __restrict__ emb,
                                                       ushort_t* __restrict__ ehi,
                                                       ushort_t* __restrict__ emd,
                                                       ushort_t* __restrict__ elo) {
    int i = blockIdx.x * 256 + threadIdx.x;
    ushort_t h, m, l;
    split3(emb[i], &h, &m, &l);
    ehi[i] = h; emd[i] = m; elo[i] = l;
}

// ---------------------------------------------------------------------------
// sum of squares of f -> atomicAdd into acc (acc pre-zeroed)
__global__ __launch_bounds__(256) void sumsq_kernel(const float* __restrict__ f,
                                                    float* __restrict__ acc, int n) {
    __shared__ float sh[256];
    float s = 0.f;
    for (int i = blockIdx.x * 256 + threadIdx.x; i < n; i += gridDim.x * 256) {
        float v = f[i];
        s = fmaf(v, v, s);
    }
    sh[threadIdx.x] = s;
    __syncthreads();
    for (int o = 128; o > 0; o >>= 1) {
        if (threadIdx.x < o) sh[threadIdx.x] += sh[threadIdx.x + o];
        __syncthreads();
    }
    if (threadIdx.x == 0) atomicAdd(acc, sh[0]);
}

// ---------------------------------------------------------------------------
// mean-pool, pn >= 8 (small patches): thread per (n,c); n=(b*pn+i)*pn+j
__global__ __launch_bounds__(256) void pool_kernel(const float* __restrict__ f,
                                                   ushort_t* __restrict__ zhi,
                                                   ushort_t* __restrict__ zmd,
                                                   ushort_t* __restrict__ zlo, int pn) {
    int tid = blockIdx.x * 256 + threadIdx.x;
    int c = tid % CH;
    int n = tid / CH;
    if (n >= BS * pn * pn) return;
    int j = n % pn, i = (n / pn) % pn, b = n / (pn * pn);
    int ps = HH / pn;
    const float* base = f + (((size_t)(b * CH + c) * HH) + i * ps) * HH + j * ps;
    float s = 0.f;
    for (int dy = 0; dy < ps; dy++)
        for (int dx = 0; dx < ps; dx++)
            s += base[dy * HH + dx];
    s *= (1.0f / (ps * ps));
    split3(s, &zhi[tid], &zmd[tid], &zlo[tid]);
}

// mean-pool, pn <= 4 (big patches): block per patch n, 8 sub-threads per c
__global__ __launch_bounds__(256) void pool_small_kernel(const float* __restrict__ f,
                                                         ushort_t* __restrict__ zhi,
                                                         ushort_t* __restrict__ zmd,
                                                         ushort_t* __restrict__ zlo, int pn) {
    int n = blockIdx.x;
    int j = n % pn, i = (n / pn) % pn, b = n / (pn * pn);
    int c = threadIdx.x & 31, sub = threadIdx.x >> 5;   // 8 subs
    int ps = HH / pn;                                    // 8/16/32
    const float* base = f + (((size_t)(b * CH + c) * HH) + i * ps) * HH + j * ps;
    float s = 0.f;
    for (int ry = sub; ry < ps; ry += 8)
        for (int rx = 0; rx < ps; rx++)
            s += base[ry * HH + rx];
    __shared__ float sh[256];
    sh[threadIdx.x] = s;     // tid = sub*32 + c
    __syncthreads();
    if (threadIdx.x < 32) {
        int cc = threadIdx.x;
        float t = 0.f;
        for (int k = 0; k < 8; k++) t += sh[k * 32 + cc];
        t *= (1.0f / (ps * ps));
        int o = n * CH + cc;
        split3(t, &zhi[o], &zmd[o], &zlo[o]);
    }
}

// ---------------------------------------------------------------------------
// MFMA argmin, fp32-grade via 3-way bf16 split (6 MFMAs).
// Block: 4 waves, each wave scans a quarter of the 256 v-tiles and applies
// them to RT row-tiles (16 rows each). Grid = N/(16*RT).
// A-frag: lane holds z[rt-tile row (lane&15)][quad*8..+7] (m120-verified).
// B-frag: lane holds emb[v-tile row (lane&15)][quad*8..+7].
// C/D: D[m=quad*4+reg][n=lane&15] (m89/m91-verified).
template <int RT>
__global__ __launch_bounds__(256) void argmin_mfma(const ushort_t* __restrict__ zhi,
                                                   const ushort_t* __restrict__ zmd,
                                                   const ushort_t* __restrict__ zlo,
                                                   const ushort_t* __restrict__ ehi,
                                                   const ushort_t* __restrict__ emd,
                                                   const ushort_t* __restrict__ elo,
                                                   const float* __restrict__ esqh,
                                                   int* __restrict__ out_idx,
                                                   float* __restrict__ hits) {
    const int tid  = threadIdx.x;
    const int wv   = tid >> 6;
    const int lane = tid & 63;
    const int col  = lane & 15;
    const int quad = lane >> 4;
    const int row0 = blockIdx.x * (16 * RT);

    short8 a1[RT], a2[RT], a3[RT];
#pragma unroll
    for (int rt = 0; rt < RT; rt++) {
        size_t off = ((size_t)(row0 + rt * 16 + col) << 5) + (quad << 3);
        a1[rt] = *(const short8*)(zhi + off);
        a2[rt] = *(const short8*)(zmd + off);
        a3[rt] = *(const short8*)(zlo + off);
    }

    float best[RT][4];
    int   bidx[RT][4];
#pragma unroll
    for (int rt = 0; rt < RT; rt++)
#pragma unroll
        for (int r = 0; r < 4; r++) { best[rt][r] = -FLT_MAX; bidx[rt][r] = 0; }

    const int t0 = wv * 64;
    for (int t = t0; t < t0 + 64; t++) {
        const int v = (t << 4) + col;
        const size_t eoff = ((size_t)v << 5) + (quad << 3);
        const short8 b1 = *(const short8*)(ehi + eoff);
        const short8 b2 = *(const short8*)(emd + eoff);
        const short8 b3 = *(const short8*)(elo + eoff);
        const float eh = esqh[v];
#pragma unroll
        for (int rt = 0; rt < RT; rt++) {
            floatx4 acc = {-eh, -eh, -eh, -eh};
            acc = __builtin_amdgcn_mfma_f32_16x16x32_bf16(a1[rt], b1, acc, 0, 0, 0);
            acc = __builtin_amdgcn_mfma_f32_16x16x32_bf16(a1[rt], b2, acc, 0, 0, 0);
            acc = __builtin_amdgcn_mfma_f32_16x16x32_bf16(a2[rt], b1, acc, 0, 0, 0);
            acc = __builtin_amdgcn_mfma_f32_16x16x32_bf16(a2[rt], b2, acc, 0, 0, 0);
            acc = __builtin_amdgcn_mfma_f32_16x16x32_bf16(a1[rt], b3, acc, 0, 0, 0);
            acc = __builtin_amdgcn_mfma_f32_16x16x32_bf16(a3[rt], b1, acc, 0, 0, 0);
#pragma unroll
            for (int r = 0; r < 4; r++) {
                // strict >: lane-local scan is increasing v -> keeps lowest v on tie
                if (acc[r] > best[rt][r]) { best[rt][r] = acc[r]; bidx[rt][r] = v; }
            }
        }
    }

    // reduce across the 16 cols (v within tile) of each quad group
#pragma unroll
    for (int m = 1; m < 16; m <<= 1) {
#pragma unroll
        for (int rt = 0; rt < RT; rt++)
#pragma unroll
            for (int r = 0; r < 4; r++) {
                float s2 = __shfl_xor(best[rt][r], m, 64);
                int   v2 = __shfl_xor(bidx[rt][r], m, 64);
                if (s2 > best[rt][r] ||
                    (s2 == best[rt][r] && v2 < bidx[rt][r])) {
                    best[rt][r] = s2; bidx[rt][r] = v2;
                }
            }
    }

    __shared__ float sbs[4 * RT * 16];
    __shared__ int   sbi[4 * RT * 16];
    if (col == 0) {
#pragma unroll
        for (int rt = 0; rt < RT; rt++)
#pragma unroll
            for (int r = 0; r < 4; r++) {
                int row = rt * 16 + (quad << 2) + r;
                sbs[wv * RT * 16 + row] = best[rt][r];
                sbi[wv * RT * 16 + row] = bidx[rt][r];
            }
    }
    __syncthreads();
    if (tid < RT * 16) {
        float s = sbs[tid];
        int   v = sbi[tid];
        for (int w = 1; w < 4; w++) {
            float s2 = sbs[w * RT * 16 + tid];
            int   v2 = sbi[w * RT * 16 + tid];
            if (s2 > s || (s2 == s && v2 < v)) { s = s2; v = v2; }
        }
        out_idx[row0 + tid] = v;
        atomicAdd(&hits[v], 1.0f);
    }
}

// ---------------------------------------------------------------------------
// bicubic weights, a=-0.75, half-pixel, edge clamp (matches ref _bicubic_mat)
__device__ inline void cubic_w(float xs, int pn, int* ix, float* w) {
    const float a = -0.75f;
    float xf = floorf(xs);
    int x0 = (int)xf;
    float t = xs - xf;
#pragma unroll
    for (int j = -1; j <= 2; j++) {
        float d = fabsf(t - (float)j);
        float ww;
        if (d < 1.0f)      ww = ((a + 2.0f) * d - (a + 3.0f)) * d * d + 1.0f;
        else if (d < 2.0f) ww = ((a * d - 5.0f * a) * d + 8.0f * a) * d - 4.0f * a;
        else               ww = 0.0f;
        int xi = x0 + j;
        xi = xi < 0 ? 0 : (xi > pn - 1 ? pn - 1 : xi);
        ix[j + 1] = xi;
        w[j + 1]  = ww;
    }
}

// Fused gather + bicubic upsample: hu[b,c,Y,X] = sum wy*wx*emb[idx[b patch]][c]
__global__ __launch_bounds__(256) void upsample_gather_kernel(const int* __restrict__ idx,
                                                              const float* __restrict__ emb,
                                                              float* __restrict__ hu, int pn) {
    int tid = blockIdx.x * 256 + threadIdx.x;   // [b][c][Y][X]
    int X = tid & 31;
    int Y = (tid >> 5) & 31;
    int c = (tid >> 10) & 31;
    int b = tid >> 15;
    float scale = (float)pn / (float)HH;
    int iy[4], ix[4];
    float wy[4], wx[4];
    cubic_w(((float)Y + 0.5f) * scale - 0.5f, pn, iy, wy);
    cubic_w(((float)X + 0.5f) * scale - 0.5f, pn, ix, wx);
    const int* ib = idx + b * pn * pn;
    float s = 0.f;
#pragma unroll
    for (int a = 0; a < 4; a++) {
        float rsum = 0.f;
#pragma unroll
        for (int b2 = 0; b2 < 4; b2++)
            rsum = fmaf(emb[(size_t)ib[iy[a] * pn + ix[b2]] * CH + c], wx[b2], rsum);
        s = fmaf(rsum, wy[a], s);
    }
    hu[tid] = s;
}

// ---------------------------------------------------------------------------
// Phi + residual update: f_rest -= 0.5*h + 0.5*(conv3x3(h)+bias)
// grid: b(32) x yt(4) x co-half(2) = 256 blocks; block 256 = tx(32) x ty(8).
__global__ __launch_bounds__(256) void conv_phi_kernel(const float* __restrict__ hin,
                                                       const float* __restrict__ w,
                                                       const float* __restrict__ bias,
                                                       float* __restrict__ frest) {
    const int chh = blockIdx.x & 1;
    const int yt  = (blockIdx.x >> 1) & 3;
    const int b   = blockIdx.x >> 3;
    const int tx  = threadIdx.x & 31;
    const int ty  = threadIdx.x >> 5;     // 0..7
    const int y0  = yt * 8;

    __shared__ float wl[16 * 32 * 12];    // 24 KB
    __shared__ float til[16 * 10 * 34];   // 21.25 KB

    {
        const float* wsrc = w + (size_t)chh * 16 * CH * 9;
        for (int i = threadIdx.x; i < 16 * 32 * 12; i += 256) {
            int k = i % 12;
            wl[i] = (k < 9) ? wsrc[(i / 12) * 9 + k] : 0.f;
        }
    }

    float acc[8][2];
    const int co0 = chh * 16 + ty * 2;
#pragma unroll
    for (int ry = 0; ry < 8; ry++) {
        acc[ry][0] = bias[co0 + 0];
        acc[ry][1] = bias[co0 + 1];
    }

    for (int cc = 0; cc < 2; cc++) {
        __syncthreads();
        for (int i = threadIdx.x; i < 16 * 10 * 34; i += 256) {
            int col = i % 34;
            int row = (i / 34) % 10;
            int cil = i / 340;
            int gy = y0 - 1 + row;
            int gx = col - 1;
            float vv = 0.f;
            if ((unsigned)gy < 32u && (unsigned)gx < 32u)
                vv = hin[(((size_t)(b * CH + cc * 16 + cil)) * HH + gy) * HH + gx];
            til[i] = vv;
        }
        __syncthreads();

        for (int cil = 0; cil < 16; cil++) {
            float in[10][3];
            const float* tp = &til[cil * 340];
#pragma unroll
            for (int rr2 = 0; rr2 < 10; rr2++)
#pragma unroll
                for (int dx = 0; dx < 3; dx++)
                    in[rr2][dx] = tp[rr2 * 34 + tx + dx];
#pragma unroll
            for (int u = 0; u < 2; u++) {
                const int col = ty * 2 + u;                 // co_local
                const float* wp = &wl[(col * 32 + cc * 16 + cil) * 12];
                float4 wa = *(const float4*)wp;
                float4 wb = *(const float4*)(wp + 4);
                float  w8 = wp[8];
#pragma unroll
                for (int ry = 0; ry < 8; ry++) {
                    float s = acc[ry][u];
                    s = fmaf(in[ry + 0][0], wa.x, s);
                    s = fmaf(in[ry + 0][1], wa.y, s);
                    s = fmaf(in[ry + 0][2], wa.z, s);
                    s = fmaf(in[ry + 1][0], wa.w, s);
                    s = fmaf(in[ry + 1][1], wb.x, s);
                    s = fmaf(in[ry + 1][2], wb.y, s);
                    s = fmaf(in[ry + 2][0], wb.z, s);
                    s = fmaf(in[ry + 2][1], wb.w, s);
                    s = fmaf(in[ry + 2][2], w8,   s);
                    acc[ry][u] = s;
                }
            }
        }
    }

#pragma unroll
    for (int ry = 0; ry < 8; ry++) {
#pragma unroll
        for (int u = 0; u < 2; u++) {
            int co = co0 + u;
            size_t off = (((size_t)(b * CH + co)) * HH + (y0 + ry)) * HH + tx;
            float hc = hin[off];
            frest[off] -= 0.5f * hc + 0.5f * acc[ry][u];
        }
    }
}

// ---------------------------------------------------------------------------
// perplexity + loss finalize (single block)
__global__ __launch_bounds__(256) void finalize_kernel(const float* __restrict__ hits,
                                                       const float* __restrict__ lacc,
                                                       float* __restrict__ outs) {
    __shared__ float sh[256];
    int t = threadIdx.x;
    float s = 0.f;
    for (int v = t; v < VV; v += 256) s += hits[v];
    sh[t] = s;
    __syncthreads();
    for (int o = 128; o > 0; o >>= 1) {
        if (t < o) sh[t] += sh[t + o];
        __syncthreads();
    }
    float total = sh[0];
    __syncthreads();
    float tot = fmaxf(total, 1.0f);
    float ent = 0.f;
    for (int v = t; v < VV; v += 256) {
        float p = hits[v] / tot;
        ent += p * logf(p + 1e-10f);
    }
    sh[t] = ent;
    __syncthreads();
    for (int o = 128; o > 0; o >>= 1) {
        if (t < o) sh[t] += sh[t + o];
        __syncthreads();
    }
    if (t == 0) {
        // loss = SN*(1+BETA)*mean(f^2) = 7.5 * sumsq / 1048576  (f_hat stays 0)
        outs[0] = 7.5f * lacc[0] * (1.0f / (float)FELEMS);
        outs[1] = expf(-sh[0]);
    }
}

// ---------------------------------------------------------------------------
extern "C" void kernel_launch(void* const* d_in, const int* in_sizes, int n_in,
                              void* d_out, int out_size, void* d_ws, size_t ws_size,
                              hipStream_t stream) {
    const float* f   = (const float*)d_in[0];   // (32,32,32,32)
    const float* emb = (const float*)d_in[1];   // (4096,32)
    const float* phw = (const float*)d_in[2];   // (4,32,32,3,3)
    const float* phb = (const float*)d_in[3];   // (4,32)
    float* out = (float*)d_out;                 // f_hat (1048576) + loss + perplexity

    float* ws      = (float*)d_ws;
    float* hits    = ws;                              // [0, 4096)
    float* esqh    = ws + 4096;                       // [4096, 8192)
    float* lacc    = ws + 8192;                       // [8192, 8448) padded
    int*   idxb    = (int*)(ws + 8448);               // 32768 ints -> [8448, 41216)
    float* frest   = ws + 41216;                      // [41216, 1089792)
    ushort_t* zhi  = (ushort_t*)(ws + 1089792);       // 1M ushort = 524288 f
    ushort_t* zmd  = (ushort_t*)(ws + 1614080);
    ushort_t* zlo  = (ushort_t*)(ws + 2138368);       // ends 2662656
    float* hup     = ws + 1089792;                    // alias over z-splits (safe:
                                                      //  hup written after argmin
                                                      //  reads z, before next pool)
    ushort_t* ehi  = (ushort_t*)(ws + 2662656);       // 131072 ushort = 65536 f
    ushort_t* emd  = (ushort_t*)(ws + 2728192);
    ushort_t* elo  = (ushort_t*)(ws + 2793728);       // ends 2859264 (11.4 MB)

    hipMemsetAsync(d_out, 0, (size_t)out_size * sizeof(float), stream);   // f_hat = 0
    hipMemsetAsync(ws, 0, (size_t)8448 * sizeof(float), stream);          // hits/lacc
    hipMemcpyAsync(frest, f, (size_t)FELEMS * sizeof(float),
                   hipMemcpyDeviceToDevice, stream);

    embsplit_kernel<<<VV * CH / 256, 256, 0, stream>>>(emb, ehi, emd, elo);
    esq_kernel<<<VV / 256, 256, 0, stream>>>(emb, esqh);
    sumsq_kernel<<<256, 256, 0, stream>>>(f, lacc, FELEMS);

    const int pns[6] = {1, 2, 4, 8, 16, 32};
    const int sel[6] = {0, 0, 1, 2, 3, 3};   // PHI_SEL

    for (int si = 0; si < 6; si++) {
        int pn = pns[si];
        int N = BS * pn * pn;                 // rows at this scale

        if (pn <= 4)
            pool_small_kernel<<<N, 256, 0, stream>>>(frest, zhi, zmd, zlo, pn);
        else
            pool_kernel<<<(N * CH) / 256, 256, 0, stream>>>(frest, zhi, zmd, zlo, pn);

        if (si == 5)
            argmin_mfma<4><<<N / 64, 256, 0, stream>>>(zhi, zmd, zlo, ehi, emd, elo,
                                                       esqh, idxb, hits);
        else if (si == 4)
            argmin_mfma<2><<<N / 32, 256, 0, stream>>>(zhi, zmd, zlo, ehi, emd, elo,
                                                       esqh, idxb, hits);
        else
            argmin_mfma<1><<<N / 16, 256, 0, stream>>>(zhi, zmd, zlo, ehi, emd, elo,
                                                       esqh, idxb, hits);

        if (si != 5) {   // si=5: f_rest is dead after argmin (f_hat never updated)
            upsample_gather_kernel<<<FELEMS / 256, 256, 0, stream>>>(idxb, emb, hup, pn);
            conv_phi_kernel<<<256, 256, 0, stream>>>(
                hup, phw + (size_t)sel[si] * CH * CH * 9,
                phb + (size_t)sel[si] * CH, frest);
        }
    }

    finalize_kernel<<<1, 256, 0, stream>>>(hits, lacc, out + (out_size - 2));
}

// Round 5
// 498.081 us; speedup vs baseline: 3.2697x; 1.3252x over previous
//
#include <hip/hip_runtime.h>
#include <math.h>
#include <float.h>

// Problem constants (B=32, C=32, H=W=32, V=4096)
#define BS    32
#define CH    32
#define HH    32
#define VV    4096
#define FELEMS (BS*CH*HH*HH)   // 1048576
#define NROWS_TOTAL 43680      // sum over scales of B*pn*pn

typedef unsigned short ushort_t;
typedef unsigned long long u64_t;
typedef __attribute__((ext_vector_type(8))) short short8;
typedef __attribute__((ext_vector_type(4))) float floatx4;

// RNE round fp32 -> bf16 bits
__device__ inline unsigned bf16_rne(float x) {
    unsigned u = __builtin_bit_cast(unsigned, x);
    return (u + 0x7FFFu + ((u >> 16) & 1u)) >> 16;
}

// 3-way bf16 split: x ~= hi + mid + lo, residual <= 2^-26 |x|
__device__ inline void split3(float x, ushort_t* h, ushort_t* m, ushort_t* l) {
    unsigned hb = bf16_rne(x);
    float r1 = x - __builtin_bit_cast(float, hb << 16);
    unsigned mb = bf16_rne(r1);
    float r2 = r1 - __builtin_bit_cast(float, mb << 16);
    unsigned lb = bf16_rne(r2);
    *h = (ushort_t)hb; *m = (ushort_t)mb; *l = (ushort_t)lb;
}

// fp32 -> sortable-descending key32 (bigger score => smaller key)
__device__ inline unsigned score_key32(float s) {
    unsigned u = __builtin_bit_cast(unsigned, s);
    unsigned m = (u & 0x80000000u) ? ~u : (u | 0x80000000u);  // monotone asc
    return ~m;                                                 // desc
}

// ---------------------------------------------------------------------------
// prep: per code v, esqh[v] = 0.5*|e|^2 and 3-way bf16 split of emb row
__global__ __launch_bounds__(256) void prep_kernel(const float* __restrict__ emb,
                                                   ushort_t* __restrict__ ehi,
                                                   ushort_t* __restrict__ emd,
                                                   ushort_t* __restrict__ elo,
                                                   float* __restrict__ esqh) {
    int v = blockIdx.x * 256 + threadIdx.x;
    const float* ep = emb + (size_t)v * CH;
    float s = 0.f;
    ushort_t h[CH], m[CH], l[CH];
#pragma unroll
    for (int i = 0; i < CH; i++) {
        float e = ep[i];
        s = fmaf(e, e, s);
        split3(e, &h[i], &m[i], &l[i]);
    }
    esqh[v] = 0.5f * s;
#pragma unroll
    for (int q = 0; q < 4; q++) {
        short8 H, M, L;
#pragma unroll
        for (int k = 0; k < 8; k++) {
            H[k] = (short)h[q * 8 + k];
            M[k] = (short)m[q * 8 + k];
            L[k] = (short)l[q * 8 + k];
        }
        *(short8*)(ehi + (size_t)v * CH + q * 8) = H;
        *(short8*)(emd + (size_t)v * CH + q * 8) = M;
        *(short8*)(elo + (size_t)v * CH + q * 8) = L;
    }
}

// ---------------------------------------------------------------------------
// mean-pool, pn >= 8: thread per (n,c); n=(b*pn+i)*pn+j
__global__ __launch_bounds__(256) void pool_kernel(const float* __restrict__ f,
                                                   ushort_t* __restrict__ zhi,
                                                   ushort_t* __restrict__ zmd,
                                                   ushort_t* __restrict__ zlo, int pn) {
    int tid = blockIdx.x * 256 + threadIdx.x;
    int c = tid % CH;
    int n = tid / CH;
    if (n >= BS * pn * pn) return;
    int j = n % pn, i = (n / pn) % pn, b = n / (pn * pn);
    int ps = HH / pn;
    const float* base = f + (((size_t)(b * CH + c) * HH) + i * ps) * HH + j * ps;
    float s = 0.f;
    for (int dy = 0; dy < ps; dy++)
        for (int dx = 0; dx < ps; dx++)
            s += base[dy * HH + dx];
    s *= (1.0f / (ps * ps));
    split3(s, &zhi[tid], &zmd[tid], &zlo[tid]);
}

// mean-pool, pn <= 4: block per patch n, 8 sub-threads per channel.
// SQ: also accumulate sum of squares of the source (used at si=0 where src=f).
template <bool SQ>
__global__ __launch_bounds__(256) void pool_small_kernel(const float* __restrict__ f,
                                                         ushort_t* __restrict__ zhi,
                                                         ushort_t* __restrict__ zmd,
                                                         ushort_t* __restrict__ zlo,
                                                         float* __restrict__ lacc, int pn) {
    int n = blockIdx.x;
    int j = n % pn, i = (n / pn) % pn, b = n / (pn * pn);
    int c = threadIdx.x & 31, sub = threadIdx.x >> 5;   // 8 subs
    int ps = HH / pn;                                    // 8/16/32
    const float* base = f + (((size_t)(b * CH + c) * HH) + i * ps) * HH + j * ps;
    float s = 0.f, s2 = 0.f;
    for (int ry = sub; ry < ps; ry += 8)
        for (int rx = 0; rx < ps; rx++) {
            float v = base[ry * HH + rx];
            s += v;
            if (SQ) s2 = fmaf(v, v, s2);
        }
    __shared__ float sh[256];
    sh[threadIdx.x] = s;
    __syncthreads();
    if (threadIdx.x < 32) {
        int cc = threadIdx.x;
        float t = 0.f;
        for (int k = 0; k < 8; k++) t += sh[k * 32 + cc];
        t *= (1.0f / (ps * ps));
        int o = n * CH + cc;
        split3(t, &zhi[o], &zmd[o], &zlo[o]);
    }
    if (SQ) {
        __syncthreads();
        sh[threadIdx.x] = s2;
        __syncthreads();
        for (int o = 128; o > 0; o >>= 1) {
            if (threadIdx.x < o) sh[threadIdx.x] += sh[threadIdx.x + o];
            __syncthreads();
        }
        if (threadIdx.x == 0) atomicAdd(lacc, sh[0]);
    }
}

// ---------------------------------------------------------------------------
// argmin core. Wave wv scans TPW v-tiles starting at tile t0+wv*TPW, applying
// them to RT 16-row tiles (A-frags in a1/a2/a3). Software-pipelined emb loads.
// Winner per row via packed-key atomicMin (max score, lowest idx on ties).
// A-frag: lane holds z[row][quad*8..+7]; B-frag: emb[v][quad*8..+7];
// D: (m=quad*4+reg, n=lane&15) -> acc[r] = score(row0+rt*16+quad*4+r, v-tile col lane&15).
template <int RT, int TPW>
__device__ inline void argmin_body(const short8* a1, const short8* a2, const short8* a3,
                                   const ushort_t* __restrict__ ehi,
                                   const ushort_t* __restrict__ emd,
                                   const ushort_t* __restrict__ elo,
                                   const float* __restrict__ esqh,
                                   u64_t* __restrict__ pk, int row0, int t0) {
    const int tid  = threadIdx.x;
    const int wv   = tid >> 6;
    const int lane = tid & 63;
    const int col  = lane & 15;
    const int quad = lane >> 4;

    float best[RT][4];
    int   bidx[RT][4];
#pragma unroll
    for (int rt = 0; rt < RT; rt++)
#pragma unroll
        for (int r = 0; r < 4; r++) { best[rt][r] = -FLT_MAX; bidx[rt][r] = 0; }

    int t = t0 + wv * TPW;
    const int tend = t + TPW;

    // prefetch tile t
    size_t eoff = ((size_t)((t << 4) + col) << 5) + (quad << 3);
    short8 nb1 = *(const short8*)(ehi + eoff);
    short8 nb2 = *(const short8*)(emd + eoff);
    short8 nb3 = *(const short8*)(elo + eoff);
    float  neh = esqh[(t << 4) + col];

    for (; t < tend; t++) {
        const short8 b1 = nb1, b2 = nb2, b3 = nb3;
        const float  eh = neh;
        const int v = (t << 4) + col;
        // prefetch t+1 (clamped) before consuming current
        const int tn = (t + 1 < tend) ? (t + 1) : t;
        const size_t eoff2 = ((size_t)((tn << 4) + col) << 5) + (quad << 3);
        nb1 = *(const short8*)(ehi + eoff2);
        nb2 = *(const short8*)(emd + eoff2);
        nb3 = *(const short8*)(elo + eoff2);
        neh = esqh[(tn << 4) + col];
#pragma unroll
        for (int rt = 0; rt < RT; rt++) {
            floatx4 acc = {-eh, -eh, -eh, -eh};
            acc = __builtin_amdgcn_mfma_f32_16x16x32_bf16(a1[rt], b1, acc, 0, 0, 0);
            acc = __builtin_amdgcn_mfma_f32_16x16x32_bf16(a1[rt], b2, acc, 0, 0, 0);
            acc = __builtin_amdgcn_mfma_f32_16x16x32_bf16(a2[rt], b1, acc, 0, 0, 0);
            acc = __builtin_amdgcn_mfma_f32_16x16x32_bf16(a2[rt], b2, acc, 0, 0, 0);
            acc = __builtin_amdgcn_mfma_f32_16x16x32_bf16(a1[rt], b3, acc, 0, 0, 0);
            acc = __builtin_amdgcn_mfma_f32_16x16x32_bf16(a3[rt], b1, acc, 0, 0, 0);
#pragma unroll
            for (int r = 0; r < 4; r++) {
                // strict >: lane scan is increasing v -> keeps lowest v on tie
                if (acc[r] > best[rt][r]) { best[rt][r] = acc[r]; bidx[rt][r] = v; }
            }
        }
    }

    // reduce across the 16 cols (v within tile) of each quad group
#pragma unroll
    for (int m = 1; m < 16; m <<= 1) {
#pragma unroll
        for (int rt = 0; rt < RT; rt++)
#pragma unroll
            for (int r = 0; r < 4; r++) {
                float s2 = __shfl_xor(best[rt][r], m, 64);
                int   v2 = __shfl_xor(bidx[rt][r], m, 64);
                if (s2 > best[rt][r] ||
                    (s2 == best[rt][r] && v2 < bidx[rt][r])) {
                    best[rt][r] = s2; bidx[rt][r] = v2;
                }
            }
    }

    __shared__ float sbs[4 * RT * 16];
    __shared__ int   sbi[4 * RT * 16];
    if (col == 0) {
#pragma unroll
        for (int rt = 0; rt < RT; rt++)
#pragma unroll
            for (int r = 0; r < 4; r++) {
                int row = rt * 16 + (quad << 2) + r;
                sbs[wv * RT * 16 + row] = best[rt][r];
                sbi[wv * RT * 16 + row] = bidx[rt][r];
            }
    }
    __syncthreads();
    if (tid < RT * 16) {
        float s = sbs[tid];
        int   v = sbi[tid];
        for (int w = 1; w < 4; w++) {
            float s2 = sbs[w * RT * 16 + tid];
            int   v2 = sbi[w * RT * 16 + tid];
            if (s2 > s || (s2 == s && v2 < v)) { s = s2; v = v2; }
        }
        u64_t key = ((u64_t)score_key32(s) << 32) | (unsigned)v;
        atomicMin(pk + row0 + tid, key);
    }
}

// generic stage: z-splits from memory. grid = (nRowBlocks, VS)
template <int RT, int VS>
__global__ __launch_bounds__(256) void argmin_stage(const ushort_t* __restrict__ zhi,
                                                    const ushort_t* __restrict__ zmd,
                                                    const ushort_t* __restrict__ zlo,
                                                    const ushort_t* __restrict__ ehi,
                                                    const ushort_t* __restrict__ emd,
                                                    const ushort_t* __restrict__ elo,
                                                    const float* __restrict__ esqh,
                                                    u64_t* __restrict__ pk) {
    const int lane = threadIdx.x & 63;
    const int col  = lane & 15;
    const int quad = lane >> 4;
    const int row0 = blockIdx.x * (16 * RT);

    short8 a1[RT], a2[RT], a3[RT];
#pragma unroll
    for (int rt = 0; rt < RT; rt++) {
        size_t off = ((size_t)(row0 + rt * 16 + col) << 5) + (quad << 3);
        a1[rt] = *(const short8*)(zhi + off);
        a2[rt] = *(const short8*)(zmd + off);
        a3[rt] = *(const short8*)(zlo + off);
    }
    argmin_body<RT, 64 / VS>(a1, a2, a3, ehi, emd, elo, esqh, pk,
                             row0, (int)blockIdx.y * (256 / VS));
}

// si=5 fused: pool is identity (pn=32, ps=1) -> split3 straight from frest.
__global__ __launch_bounds__(256) void argmin5_fused(const float* __restrict__ frest,
                                                     const ushort_t* __restrict__ ehi,
                                                     const ushort_t* __restrict__ emd,
                                                     const ushort_t* __restrict__ elo,
                                                     const float* __restrict__ esqh,
                                                     u64_t* __restrict__ pk) {
    const int lane = threadIdx.x & 63;
    const int col  = lane & 15;
    const int quad = lane >> 4;
    const int row0 = blockIdx.x * 64;   // RT=4

    short8 a1[4], a2[4], a3[4];
#pragma unroll
    for (int rt = 0; rt < 4; rt++) {
        int n = row0 + rt * 16 + col;               // row = (b*32+i)*32+j
        int b = n >> 10, i = (n >> 5) & 31, j = n & 31;
        const float* p = frest + ((((size_t)(b * CH + quad * 8)) * HH + i) * HH + j);
#pragma unroll
        for (int k = 0; k < 8; k++) {
            ushort_t h, m, l;
            split3(p[(size_t)k * (HH * HH)], &h, &m, &l);   // c stride = 1024
            a1[rt][k] = (short)h; a2[rt][k] = (short)m; a3[rt][k] = (short)l;
        }
    }
    argmin_body<4, 64>(a1, a2, a3, ehi, emd, elo, esqh, pk, row0, 0);
}

// ---------------------------------------------------------------------------
// bicubic weights, a=-0.75, half-pixel, edge clamp (matches ref _bicubic_mat)
__device__ inline void cubic_w(float xs, int pn, int* ix, float* w) {
    const float a = -0.75f;
    float xf = floorf(xs);
    int x0 = (int)xf;
    float t = xs - xf;
#pragma unroll
    for (int j = -1; j <= 2; j++) {
        float d = fabsf(t - (float)j);
        float ww;
        if (d < 1.0f)      ww = ((a + 2.0f) * d - (a + 3.0f)) * d * d + 1.0f;
        else if (d < 2.0f) ww = ((a * d - 5.0f * a) * d + 8.0f * a) * d - 4.0f * a;
        else               ww = 0.0f;
        int xi = x0 + j;
        xi = xi < 0 ? 0 : (xi > pn - 1 ? pn - 1 : xi);
        ix[j + 1] = xi;
        w[j + 1]  = ww;
    }
}

// Fused gather + bicubic upsample from packed keys (idx = low 32 bits)
__global__ __launch_bounds__(256) void upsample_gather_kernel(const u64_t* __restrict__ pk,
                                                              const float* __restrict__ emb,
                                                              float* __restrict__ hu, int pn) {
    int tid = blockIdx.x * 256 + threadIdx.x;   // [b][c][Y][X]
    int X = tid & 31;
    int Y = (tid >> 5) & 31;
    int c = (tid >> 10) & 31;
    int b = tid >> 15;
    float scale = (float)pn / (float)HH;
    int iy[4], ix[4];
    float wy[4], wx[4];
    cubic_w(((float)Y + 0.5f) * scale - 0.5f, pn, iy, wy);
    cubic_w(((float)X + 0.5f) * scale - 0.5f, pn, ix, wx);
    const u64_t* ib = pk + b * pn * pn;
    float s = 0.f;
#pragma unroll
    for (int a = 0; a < 4; a++) {
        float rsum = 0.f;
#pragma unroll
        for (int b2 = 0; b2 < 4; b2++) {
            int idx = (int)(unsigned)(ib[iy[a] * pn + ix[b2]] & 0xFFFFFFFFull);
            rsum = fmaf(emb[(size_t)idx * CH + c], wx[b2], rsum);
        }
        s = fmaf(rsum, wy[a], s);
    }
    hu[tid] = s;
}

// ---------------------------------------------------------------------------
// Phi + residual: dst = src - (0.5*h + 0.5*(conv3x3(h)+bias))
// grid: b(32) x yt(4) x co-half(2) = 256 blocks; block 256 = tx(32) x ty(8).
__global__ __launch_bounds__(256) void conv_phi_kernel(const float* __restrict__ hin,
                                                       const float* __restrict__ w,
                                                       const float* __restrict__ bias,
                                                       const float* __restrict__ src,
                                                       float* __restrict__ dst) {
    const int chh = blockIdx.x & 1;
    const int yt  = (blockIdx.x >> 1) & 3;
    const int b   = blockIdx.x >> 3;
    const int tx  = threadIdx.x & 31;
    const int ty  = threadIdx.x >> 5;     // 0..7
    const int y0  = yt * 8;

    __shared__ float wl[16 * 32 * 12];    // 24 KB
    __shared__ float til[16 * 10 * 34];   // 21.25 KB

    {
        const float* wsrc = w + (size_t)chh * 16 * CH * 9;
        for (int i = threadIdx.x; i < 16 * 32 * 12; i += 256) {
            int k = i % 12;
            wl[i] = (k < 9) ? wsrc[(i / 12) * 9 + k] : 0.f;
        }
    }

    float acc[8][2];
    const int co0 = chh * 16 + ty * 2;
#pragma unroll
    for (int ry = 0; ry < 8; ry++) {
        acc[ry][0] = bias[co0 + 0];
        acc[ry][1] = bias[co0 + 1];
    }

    for (int cc = 0; cc < 2; cc++) {
        __syncthreads();
        for (int i = threadIdx.x; i < 16 * 10 * 34; i += 256) {
            int col = i % 34;
            int row = (i / 34) % 10;
            int cil = i / 340;
            int gy = y0 - 1 + row;
            int gx = col - 1;
            float vv = 0.f;
            if ((unsigned)gy < 32u && (unsigned)gx < 32u)
                vv = hin[(((size_t)(b * CH + cc * 16 + cil)) * HH + gy) * HH + gx];
            til[i] = vv;
        }
        __syncthreads();

        for (int cil = 0; cil < 16; cil++) {
            float in[10][3];
            const float* tp = &til[cil * 340];
#pragma unroll
            for (int rr2 = 0; rr2 < 10; rr2++)
#pragma unroll
                for (int dx = 0; dx < 3; dx++)
                    in[rr2][dx] = tp[rr2 * 34 + tx + dx];
#pragma unroll
            for (int u = 0; u < 2; u++) {
                const int col = ty * 2 + u;                 // co_local
                const float* wp = &wl[(col * 32 + cc * 16 + cil) * 12];
                float4 wa = *(const float4*)wp;
                float4 wb = *(const float4*)(wp + 4);
                float  w8 = wp[8];
#pragma unroll
                for (int ry = 0; ry < 8; ry++) {
                    float s = acc[ry][u];
                    s = fmaf(in[ry + 0][0], wa.x, s);
                    s = fmaf(in[ry + 0][1], wa.y, s);
                    s = fmaf(in[ry + 0][2], wa.z, s);
                    s = fmaf(in[ry + 1][0], wa.w, s);
                    s = fmaf(in[ry + 1][1], wb.x, s);
                    s = fmaf(in[ry + 1][2], wb.y, s);
                    s = fmaf(in[ry + 2][0], wb.z, s);
                    s = fmaf(in[ry + 2][1], wb.w, s);
                    s = fmaf(in[ry + 2][2], w8,   s);
                    acc[ry][u] = s;
                }
            }
        }
    }

#pragma unroll
    for (int ry = 0; ry < 8; ry++) {
#pragma unroll
        for (int u = 0; u < 2; u++) {
            int co = co0 + u;
            size_t off = (((size_t)(b * CH + co)) * HH + (y0 + ry)) * HH + tx;
            float hc = hin[off];
            dst[off] = src[off] - (0.5f * hc + 0.5f * acc[ry][u]);
        }
    }
}

// ---------------------------------------------------------------------------
// hits bincount over all scales' packed winners
__global__ __launch_bounds__(256) void bincount_kernel(const u64_t* __restrict__ pk,
                                                       float* __restrict__ hits, int n) {
    int i = blockIdx.x * 256 + threadIdx.x;
    if (i < n) {
        int idx = (int)(unsigned)(pk[i] & 0xFFFFFFFFull);
        atomicAdd(&hits[idx], 1.0f);
    }
}

// ---------------------------------------------------------------------------
// perplexity + loss finalize (single block)
__global__ __launch_bounds__(256) void finalize_kernel(const float* __restrict__ hits,
                                                       const float* __restrict__ lacc,
                                                       float* __restrict__ outs) {
    __shared__ float sh[256];
    int t = threadIdx.x;
    float s = 0.f;
    for (int v = t; v < VV; v += 256) s += hits[v];
    sh[t] = s;
    __syncthreads();
    for (int o = 128; o > 0; o >>= 1) {
        if (t < o) sh[t] += sh[t + o];
        __syncthreads();
    }
    float total = sh[0];
    __syncthreads();
    float tot = fmaxf(total, 1.0f);
    float ent = 0.f;
    for (int v = t; v < VV; v += 256) {
        float p = hits[v] / tot;
        ent += p * logf(p + 1e-10f);
    }
    sh[t] = ent;
    __syncthreads();
    for (int o = 128; o > 0; o >>= 1) {
        if (t < o) sh[t] += sh[t + o];
        __syncthreads();
    }
    if (t == 0) {
        // loss = SN*(1+BETA)*mean(f^2) = 7.5 * sumsq / 1048576  (f_hat stays 0)
        outs[0] = 7.5f * lacc[0] * (1.0f / (float)FELEMS);
        outs[1] = expf(-sh[0]);
    }
}

// ---------------------------------------------------------------------------
extern "C" void kernel_launch(void* const* d_in, const int* in_sizes, int n_in,
                              void* d_out, int out_size, void* d_ws, size_t ws_size,
                              hipStream_t stream) {
    const float* f   = (const float*)d_in[0];   // (32,32,32,32)
    const float* emb = (const float*)d_in[1];   // (4096,32)
    const float* phw = (const float*)d_in[2];   // (4,32,32,3,3)
    const float* phb = (const float*)d_in[3];   // (4,32)
    float* out = (float*)d_out;                 // f_hat (1048576) + loss + perplexity

    float* ws      = (float*)d_ws;
    float* hits    = ws;                              // [0, 4096)
    float* esqh    = ws + 4096;                       // [4096, 8192)
    float* lacc    = ws + 8192;                       // [8192, 8448) padded
    u64_t* pkbase  = (u64_t*)(ws + 8448);             // 43680 u64 -> [8448, 95808)
    float* frest   = ws + 95808;                      // [95808, 1144384)
    ushort_t* zhi  = (ushort_t*)(ws + 1144384);       // 262144 us (si<=4 max N=8192)
    ushort_t* zmd  = (ushort_t*)(ws + 1275456);
    ushort_t* zlo  = (ushort_t*)(ws + 1406528);       // ends 1537600
    float* hup     = ws + 1537600;                    // [1537600, 2586176)
    ushort_t* ehi  = (ushort_t*)(ws + 2586176);       // 131072 us each
    ushort_t* emd  = (ushort_t*)(ws + 2651712);
    ushort_t* elo  = (ushort_t*)(ws + 2717248);       // ends 2782784 (11.1 MB)

    hipMemsetAsync(d_out, 0, (size_t)out_size * sizeof(float), stream);   // f_hat = 0
    hipMemsetAsync(ws, 0, (size_t)8448 * sizeof(float), stream);          // hits/lacc
    hipMemsetAsync(pkbase, 0xFF, (size_t)NROWS_TOTAL * 8, stream);        // pk = +inf key

    prep_kernel<<<VV / 256, 256, 0, stream>>>(emb, ehi, emd, elo, esqh);

    const int pns[6]   = {1, 2, 4, 8, 16, 32};
    const int sel[6]   = {0, 0, 1, 2, 3, 3};            // PHI_SEL
    const int pkoff[6] = {0, 32, 160, 672, 2720, 10912};

    for (int si = 0; si < 6; si++) {
        int pn = pns[si];
        int N = BS * pn * pn;
        u64_t* pk = pkbase + pkoff[si];
        const float* srcf = (si == 0) ? f : frest;      // frest not yet written at si=0

        if (si == 5) {
            argmin5_fused<<<512, 256, 0, stream>>>(frest, ehi, emd, elo, esqh, pk);
        } else {
            if (pn <= 4) {
                if (si == 0)
                    pool_small_kernel<true><<<N, 256, 0, stream>>>(srcf, zhi, zmd, zlo, lacc, pn);
                else
                    pool_small_kernel<false><<<N, 256, 0, stream>>>(srcf, zhi, zmd, zlo, lacc, pn);
            } else {
                pool_kernel<<<(N * CH) / 256, 256, 0, stream>>>(srcf, zhi, zmd, zlo, pn);
            }
            if (si <= 2)        // N=32/128/512 -> grids 16/64/256
                argmin_stage<1, 8><<<dim3(N / 16, 8), 256, 0, stream>>>(zhi, zmd, zlo, ehi, emd, elo, esqh, pk);
            else if (si == 3)   // N=2048 -> grid 512
                argmin_stage<1, 4><<<dim3(N / 16, 4), 256, 0, stream>>>(zhi, zmd, zlo, ehi, emd, elo, esqh, pk);
            else                // si=4, N=8192 -> grid 512
                argmin_stage<2, 2><<<dim3(N / 32, 2), 256, 0, stream>>>(zhi, zmd, zlo, ehi, emd, elo, esqh, pk);

            upsample_gather_kernel<<<FELEMS / 256, 256, 0, stream>>>(pk, emb, hup, pn);
            conv_phi_kernel<<<256, 256, 0, stream>>>(
                hup, phw + (size_t)sel[si] * CH * CH * 9,
                phb + (size_t)sel[si] * CH, srcf, frest);
        }
    }

    bincount_kernel<<<(NROWS_TOTAL + 255) / 256, 256, 0, stream>>>(pkbase, hits, NROWS_TOTAL);
    finalize_kernel<<<1, 256, 0, stream>>>(hits, lacc, out + (out_size - 2));
}

// Round 6
// 448.284 us; speedup vs baseline: 3.6329x; 1.1111x over previous
//
#include <hip/hip_runtime.h>
#include <math.h>
#include <float.h>

// Problem constants (B=32, C=32, H=W=32, V=4096)
#define BS    32
#define CH    32
#define HH    32
#define VV    4096
#define FELEMS (BS*CH*HH*HH)   // 1048576
#define NROWS_TOTAL 43680      // sum over scales of B*pn*pn

typedef unsigned short ushort_t;
typedef unsigned long long u64_t;
typedef __attribute__((ext_vector_type(8))) short short8;
typedef __attribute__((ext_vector_type(4))) float floatx4;

// RNE round fp32 -> bf16 bits
__device__ inline unsigned bf16_rne(float x) {
    unsigned u = __builtin_bit_cast(unsigned, x);
    return (u + 0x7FFFu + ((u >> 16) & 1u)) >> 16;
}

// 3-way bf16 split: x ~= hi + mid + lo, residual <= 2^-26 |x|
__device__ inline void split3(float x, ushort_t* h, ushort_t* m, ushort_t* l) {
    unsigned hb = bf16_rne(x);
    float r1 = x - __builtin_bit_cast(float, hb << 16);
    unsigned mb = bf16_rne(r1);
    float r2 = r1 - __builtin_bit_cast(float, mb << 16);
    unsigned lb = bf16_rne(r2);
    *h = (ushort_t)hb; *m = (ushort_t)mb; *l = (ushort_t)lb;
}

// fp32 -> sortable-descending key32 (bigger score => smaller key)
__device__ inline unsigned score_key32(float s) {
    unsigned u = __builtin_bit_cast(unsigned, s);
    unsigned m = (u & 0x80000000u) ? ~u : (u | 0x80000000u);  // monotone asc
    return ~m;                                                 // desc
}

// ---------------------------------------------------------------------------
// prep: per code v, nesqh[v] = -0.5*|e|^2 and 3-way bf16 split of emb row
__global__ __launch_bounds__(256) void prep_kernel(const float* __restrict__ emb,
                                                   ushort_t* __restrict__ ehi,
                                                   ushort_t* __restrict__ emd,
                                                   ushort_t* __restrict__ elo,
                                                   float* __restrict__ nesqh) {
    int v = blockIdx.x * 256 + threadIdx.x;
    const float* ep = emb + (size_t)v * CH;
    float s = 0.f;
    ushort_t h[CH], m[CH], l[CH];
#pragma unroll
    for (int i = 0; i < CH; i++) {
        float e = ep[i];
        s = fmaf(e, e, s);
        split3(e, &h[i], &m[i], &l[i]);
    }
    nesqh[v] = -0.5f * s;
#pragma unroll
    for (int q = 0; q < 4; q++) {
        short8 H, M, L;
#pragma unroll
        for (int k = 0; k < 8; k++) {
            H[k] = (short)h[q * 8 + k];
            M[k] = (short)m[q * 8 + k];
            L[k] = (short)l[q * 8 + k];
        }
        *(short8*)(ehi + (size_t)v * CH + q * 8) = H;
        *(short8*)(emd + (size_t)v * CH + q * 8) = M;
        *(short8*)(elo + (size_t)v * CH + q * 8) = L;
    }
}

// ---------------------------------------------------------------------------
// mean-pool, pn >= 8: thread per (n,c); n=(b*pn+i)*pn+j
__global__ __launch_bounds__(256) void pool_kernel(const float* __restrict__ f,
                                                   ushort_t* __restrict__ zhi,
                                                   ushort_t* __restrict__ zmd,
                                                   ushort_t* __restrict__ zlo, int pn) {
    int tid = blockIdx.x * 256 + threadIdx.x;
    int c = tid % CH;
    int n = tid / CH;
    if (n >= BS * pn * pn) return;
    int j = n % pn, i = (n / pn) % pn, b = n / (pn * pn);
    int ps = HH / pn;
    const float* base = f + (((size_t)(b * CH + c) * HH) + i * ps) * HH + j * ps;
    float s = 0.f;
    for (int dy = 0; dy < ps; dy++)
        for (int dx = 0; dx < ps; dx++)
            s += base[dy * HH + dx];
    s *= (1.0f / (ps * ps));
    split3(s, &zhi[tid], &zmd[tid], &zlo[tid]);
}

// mean-pool, pn <= 4: block per patch n, 8 sub-threads per channel.
// SQ: also accumulate sum of squares of the source (used at si=0 where src=f).
template <bool SQ>
__global__ __launch_bounds__(256) void pool_small_kernel(const float* __restrict__ f,
                                                         ushort_t* __restrict__ zhi,
                                                         ushort_t* __restrict__ zmd,
                                                         ushort_t* __restrict__ zlo,
                                                         float* __restrict__ lacc, int pn) {
    int n = blockIdx.x;
    int j = n % pn, i = (n / pn) % pn, b = n / (pn * pn);
    int c = threadIdx.x & 31, sub = threadIdx.x >> 5;   // 8 subs
    int ps = HH / pn;                                    // 8/16/32
    const float* base = f + (((size_t)(b * CH + c) * HH) + i * ps) * HH + j * ps;
    float s = 0.f, s2 = 0.f;
    for (int ry = sub; ry < ps; ry += 8)
        for (int rx = 0; rx < ps; rx++) {
            float v = base[ry * HH + rx];
            s += v;
            if (SQ) s2 = fmaf(v, v, s2);
        }
    __shared__ float sh[256];
    sh[threadIdx.x] = s;
    __syncthreads();
    if (threadIdx.x < 32) {
        int cc = threadIdx.x;
        float t = 0.f;
        for (int k = 0; k < 8; k++) t += sh[k * 32 + cc];
        t *= (1.0f / (ps * ps));
        int o = n * CH + cc;
        split3(t, &zhi[o], &zmd[o], &zlo[o]);
    }
    if (SQ) {
        __syncthreads();
        sh[threadIdx.x] = s2;
        __syncthreads();
        for (int o = 128; o > 0; o >>= 1) {
            if (threadIdx.x < o) sh[threadIdx.x] += sh[threadIdx.x + o];
            __syncthreads();
        }
        if (threadIdx.x == 0) atomicAdd(lacc, sh[0]);
    }
}

// ---------------------------------------------------------------------------
// argmin core. Wave wv scans TPW v-tiles starting at t0+wv*TPW, applying them
// to RT 16-row tiles (A-frags in a1/a2/a3). Software-pipelined emb loads.
// Winner per row merged cross-block via packed-key atomicMin
// (max score, lowest idx on ties -> identical to jnp.argmin).
template <int RT, int TPW>
__device__ inline void argmin_body(const short8* a1, const short8* a2, const short8* a3,
                                   const ushort_t* __restrict__ ehi,
                                   const ushort_t* __restrict__ emd,
                                   const ushort_t* __restrict__ elo,
                                   const float* __restrict__ nesqh,
                                   u64_t* __restrict__ pk, int row0, int t0) {
    const int tid  = threadIdx.x;
    const int wv   = tid >> 6;
    const int lane = tid & 63;
    const int col  = lane & 15;
    const int quad = lane >> 4;

    float best[RT][4];
    int   bidx[RT][4];
#pragma unroll
    for (int rt = 0; rt < RT; rt++)
#pragma unroll
        for (int r = 0; r < 4; r++) { best[rt][r] = -FLT_MAX; bidx[rt][r] = 0; }

    int t = t0 + wv * TPW;
    const int tend = t + TPW;

    // prefetch tile t
    size_t eoff = ((size_t)((t << 4) + col) << 5) + (quad << 3);
    short8 nb1 = *(const short8*)(ehi + eoff);
    short8 nb2 = *(const short8*)(emd + eoff);
    short8 nb3 = *(const short8*)(elo + eoff);
    float  neh = nesqh[(t << 4) + col];

    for (; t < tend; t++) {
        const short8 b1 = nb1, b2 = nb2, b3 = nb3;
        const float  eh = neh;
        const int v = (t << 4) + col;
        // prefetch t+1 (clamped) before consuming current
        const int tn = (t + 1 < tend) ? (t + 1) : t;
        const size_t eoff2 = ((size_t)((tn << 4) + col) << 5) + (quad << 3);
        nb1 = *(const short8*)(ehi + eoff2);
        nb2 = *(const short8*)(emd + eoff2);
        nb3 = *(const short8*)(elo + eoff2);
        neh = nesqh[(tn << 4) + col];
#pragma unroll
        for (int rt = 0; rt < RT; rt++) {
            floatx4 acc = {eh, eh, eh, eh};
            acc = __builtin_amdgcn_mfma_f32_16x16x32_bf16(a1[rt], b1, acc, 0, 0, 0);
            acc = __builtin_amdgcn_mfma_f32_16x16x32_bf16(a1[rt], b2, acc, 0, 0, 0);
            acc = __builtin_amdgcn_mfma_f32_16x16x32_bf16(a2[rt], b1, acc, 0, 0, 0);
            acc = __builtin_amdgcn_mfma_f32_16x16x32_bf16(a2[rt], b2, acc, 0, 0, 0);
            acc = __builtin_amdgcn_mfma_f32_16x16x32_bf16(a1[rt], b3, acc, 0, 0, 0);
            acc = __builtin_amdgcn_mfma_f32_16x16x32_bf16(a3[rt], b1, acc, 0, 0, 0);
#pragma unroll
            for (int r = 0; r < 4; r++) {
                // strict >: lane scan is increasing v -> keeps lowest v on tie
                if (acc[r] > best[rt][r]) { best[rt][r] = acc[r]; bidx[rt][r] = v; }
            }
        }
    }

    // reduce across the 16 cols (v within tile) of each quad group
#pragma unroll
    for (int m = 1; m < 16; m <<= 1) {
#pragma unroll
        for (int rt = 0; rt < RT; rt++)
#pragma unroll
            for (int r = 0; r < 4; r++) {
                float s2 = __shfl_xor(best[rt][r], m, 64);
                int   v2 = __shfl_xor(bidx[rt][r], m, 64);
                if (s2 > best[rt][r] ||
                    (s2 == best[rt][r] && v2 < bidx[rt][r])) {
                    best[rt][r] = s2; bidx[rt][r] = v2;
                }
            }
    }

    __shared__ float sbs[4 * RT * 16];
    __shared__ int   sbi[4 * RT * 16];
    if (col == 0) {
#pragma unroll
        for (int rt = 0; rt < RT; rt++)
#pragma unroll
            for (int r = 0; r < 4; r++) {
                int row = rt * 16 + (quad << 2) + r;
                sbs[wv * RT * 16 + row] = best[rt][r];
                sbi[wv * RT * 16 + row] = bidx[rt][r];
            }
    }
    __syncthreads();
    if (tid < RT * 16) {
        float s = sbs[tid];
        int   v = sbi[tid];
        for (int w = 1; w < 4; w++) {
            float s2 = sbs[w * RT * 16 + tid];
            int   v2 = sbi[w * RT * 16 + tid];
            if (s2 > s || (s2 == s && v2 < v)) { s = s2; v = v2; }
        }
        u64_t key = ((u64_t)score_key32(s) << 32) | (unsigned)v;
        atomicMin(pk + row0 + tid, key);
    }
}

// generic stage: z-splits from memory. grid = (nRowBlocks, VS)
template <int RT, int VS>
__global__ __launch_bounds__(256) void argmin_stage(const ushort_t* __restrict__ zhi,
                                                    const ushort_t* __restrict__ zmd,
                                                    const ushort_t* __restrict__ zlo,
                                                    const ushort_t* __restrict__ ehi,
                                                    const ushort_t* __restrict__ emd,
                                                    const ushort_t* __restrict__ elo,
                                                    const float* __restrict__ nesqh,
                                                    u64_t* __restrict__ pk) {
    const int lane = threadIdx.x & 63;
    const int col  = lane & 15;
    const int quad = lane >> 4;
    const int row0 = blockIdx.x * (16 * RT);

    short8 a1[RT], a2[RT], a3[RT];
#pragma unroll
    for (int rt = 0; rt < RT; rt++) {
        size_t off = ((size_t)(row0 + rt * 16 + col) << 5) + (quad << 3);
        a1[rt] = *(const short8*)(zhi + off);
        a2[rt] = *(const short8*)(zmd + off);
        a3[rt] = *(const short8*)(zlo + off);
    }
    argmin_body<RT, 64 / VS>(a1, a2, a3, ehi, emd, elo, nesqh, pk,
                             row0, (int)blockIdx.y * (256 / VS));
}

// si=5 fused: pool is identity (pn=32, ps=1) -> split3 straight from frest.
// grid = (512, 4): VS=4, each wave scans 16 tiles.
__global__ __launch_bounds__(256) void argmin5_fused(const float* __restrict__ frest,
                                                     const ushort_t* __restrict__ ehi,
                                                     const ushort_t* __restrict__ emd,
                                                     const ushort_t* __restrict__ elo,
                                                     const float* __restrict__ nesqh,
                                                     u64_t* __restrict__ pk) {
    const int lane = threadIdx.x & 63;
    const int col  = lane & 15;
    const int quad = lane >> 4;
    const int row0 = blockIdx.x * 64;   // RT=4

    short8 a1[4], a2[4], a3[4];
#pragma unroll
    for (int rt = 0; rt < 4; rt++) {
        int n = row0 + rt * 16 + col;               // row = (b*32+i)*32+j
        int b = n >> 10, i = (n >> 5) & 31, j = n & 31;
        const float* p = frest + ((((size_t)(b * CH + quad * 8)) * HH + i) * HH + j);
#pragma unroll
        for (int k = 0; k < 8; k++) {
            ushort_t h, m, l;
            split3(p[(size_t)k * (HH * HH)], &h, &m, &l);   // c stride = 1024
            a1[rt][k] = (short)h; a2[rt][k] = (short)m; a3[rt][k] = (short)l;
        }
    }
    argmin_body<4, 16>(a1, a2, a3, ehi, emd, elo, nesqh, pk,
                       row0, (int)blockIdx.y * 64);
}

// ---------------------------------------------------------------------------
// bicubic weights, a=-0.75, half-pixel, edge clamp (matches ref _bicubic_mat)
__device__ inline void cubic_w(float xs, int pn, int* ix, float* w) {
    const float a = -0.75f;
    float xf = floorf(xs);
    int x0 = (int)xf;
    float t = xs - xf;
#pragma unroll
    for (int j = -1; j <= 2; j++) {
        float d = fabsf(t - (float)j);
        float ww;
        if (d < 1.0f)      ww = ((a + 2.0f) * d - (a + 3.0f)) * d * d + 1.0f;
        else if (d < 2.0f) ww = ((a * d - 5.0f * a) * d + 8.0f * a) * d - 4.0f * a;
        else               ww = 0.0f;
        int xi = x0 + j;
        xi = xi < 0 ? 0 : (xi > pn - 1 ? pn - 1 : xi);
        ix[j + 1] = xi;
        w[j + 1]  = ww;
    }
}

// Fused gather + bicubic upsample from packed keys (idx = low 32 bits).
// Thread mapping: c in the low 5 bits -> the 16 emb-row gathers are fully
// coalesced (lane c reads emb[row][c], one 128B line per row) and the pk
// loads are wave-broadcast. hu write is strided (c-major layout) -> L2.
__global__ __launch_bounds__(256) void upsample_gather_kernel(const u64_t* __restrict__ pk,
                                                              const float* __restrict__ emb,
                                                              float* __restrict__ hu, int pn) {
    int tid = blockIdx.x * 256 + threadIdx.x;   // [b][Y][X][c]
    int c = tid & 31;
    int X = (tid >> 5) & 31;
    int Y = (tid >> 10) & 31;
    int b = tid >> 15;
    float scale = (float)pn / (float)HH;
    int iy[4], ix[4];
    float wy[4], wx[4];
    cubic_w(((float)Y + 0.5f) * scale - 0.5f, pn, iy, wy);
    cubic_w(((float)X + 0.5f) * scale - 0.5f, pn, ix, wx);
    const u64_t* ib = pk + b * pn * pn;
    float s = 0.f;
#pragma unroll
    for (int a = 0; a < 4; a++) {
        float rsum = 0.f;
#pragma unroll
        for (int b2 = 0; b2 < 4; b2++) {
            int idx = (int)(unsigned)(ib[iy[a] * pn + ix[b2]] & 0xFFFFFFFFull);
            rsum = fmaf(emb[(size_t)idx * CH + c], wx[b2], rsum);
        }
        s = fmaf(rsum, wy[a], s);
    }
    hu[(((size_t)(b * CH + c)) * HH + Y) * HH + X] = s;
}

// ---------------------------------------------------------------------------
// Phi + residual: dst = src - (0.5*h + 0.5*(conv3x3(h)+bias))
// grid: b(32) x yt(4) x co-half(2) = 256 blocks; block 256 = tx(32) x ty(8).
__global__ __launch_bounds__(256) void conv_phi_kernel(const float* __restrict__ hin,
                                                       const float* __restrict__ w,
                                                       const float* __restrict__ bias,
                                                       const float* __restrict__ src,
                                                       float* __restrict__ dst) {
    const int chh = blockIdx.x & 1;
    const int yt  = (blockIdx.x >> 1) & 3;
    const int b   = blockIdx.x >> 3;
    const int tx  = threadIdx.x & 31;
    const int ty  = threadIdx.x >> 5;     // 0..7
    const int y0  = yt * 8;

    __shared__ float wl[16 * 32 * 12];    // 24 KB
    __shared__ float til[16 * 10 * 34];   // 21.25 KB

    {
        const float* wsrc = w + (size_t)chh * 16 * CH * 9;
        for (int i = threadIdx.x; i < 16 * 32 * 12; i += 256) {
            int k = i % 12;
            wl[i] = (k < 9) ? wsrc[(i / 12) * 9 + k] : 0.f;
        }
    }

    float acc[8][2];
    const int co0 = chh * 16 + ty * 2;
#pragma unroll
    for (int ry = 0; ry < 8; ry++) {
        acc[ry][0] = bias[co0 + 0];
        acc[ry][1] = bias[co0 + 1];
    }

    for (int cc = 0; cc < 2; cc++) {
        __syncthreads();
        for (int i = threadIdx.x; i < 16 * 10 * 34; i += 256) {
            int col = i % 34;
            int row = (i / 34) % 10;
            int cil = i / 340;
            int gy = y0 - 1 + row;
            int gx = col - 1;
            float vv = 0.f;
            if ((unsigned)gy < 32u && (unsigned)gx < 32u)
                vv = hin[(((size_t)(b * CH + cc * 16 + cil)) * HH + gy) * HH + gx];
            til[i] = vv;
        }
        __syncthreads();

        for (int cil = 0; cil < 16; cil++) {
            float in[10][3];
            const float* tp = &til[cil * 340];
#pragma unroll
            for (int rr2 = 0; rr2 < 10; rr2++)
#pragma unroll
                for (int dx = 0; dx < 3; dx++)
                    in[rr2][dx] = tp[rr2 * 34 + tx + dx];
#pragma unroll
            for (int u = 0; u < 2; u++) {
                const int col = ty * 2 + u;                 // co_local
                const float* wp = &wl[(col * 32 + cc * 16 + cil) * 12];
                float4 wa = *(const float4*)wp;
                float4 wb = *(const float4*)(wp + 4);
                float  w8 = wp[8];
#pragma unroll
                for (int ry = 0; ry < 8; ry++) {
                    float s = acc[ry][u];
                    s = fmaf(in[ry + 0][0], wa.x, s);
                    s = fmaf(in[ry + 0][1], wa.y, s);
                    s = fmaf(in[ry + 0][2], wa.z, s);
                    s = fmaf(in[ry + 1][0], wa.w, s);
                    s = fmaf(in[ry + 1][1], wb.x, s);
                    s = fmaf(in[ry + 1][2], wb.y, s);
                    s = fmaf(in[ry + 2][0], wb.z, s);
                    s = fmaf(in[ry + 2][1], wb.w, s);
                    s = fmaf(in[ry + 2][2], w8,   s);
                    acc[ry][u] = s;
                }
            }
        }
    }

#pragma unroll
    for (int ry = 0; ry < 8; ry++) {
#pragma unroll
        for (int u = 0; u < 2; u++) {
            int co = co0 + u;
            size_t off = (((size_t)(b * CH + co)) * HH + (y0 + ry)) * HH + tx;
            float hc = hin[off];
            dst[off] = src[off] - (0.5f * hc + 0.5f * acc[ry][u]);
        }
    }
}

// ---------------------------------------------------------------------------
// hits bincount over all scales' packed winners
__global__ __launch_bounds__(256) void bincount_kernel(const u64_t* __restrict__ pk,
                                                       float* __restrict__ hits, int n) {
    int i = blockIdx.x * 256 + threadIdx.x;
    if (i < n) {
        int idx = (int)(unsigned)(pk[i] & 0xFFFFFFFFull);
        atomicAdd(&hits[idx], 1.0f);
    }
}

// ---------------------------------------------------------------------------
// perplexity + loss finalize (single block)
__global__ __launch_bounds__(256) void finalize_kernel(const float* __restrict__ hits,
                                                       const float* __restrict__ lacc,
                                                       float* __restrict__ outs) {
    __shared__ float sh[256];
    int t = threadIdx.x;
    float s = 0.f;
    for (int v = t; v < VV; v += 256) s += hits[v];
    sh[t] = s;
    __syncthreads();
    for (int o = 128; o > 0; o >>= 1) {
        if (t < o) sh[t] += sh[t + o];
        __syncthreads();
    }
    float total = sh[0];
    __syncthreads();
    float tot = fmaxf(total, 1.0f);
    float ent = 0.f;
    for (int v = t; v < VV; v += 256) {
        float p = hits[v] / tot;
        ent += p * logf(p + 1e-10f);
    }
    sh[t] = ent;
    __syncthreads();
    for (int o = 128; o > 0; o >>= 1) {
        if (t < o) sh[t] += sh[t + o];
        __syncthreads();
    }
    if (t == 0) {
        // loss = SN*(1+BETA)*mean(f^2) = 7.5 * sumsq / 1048576  (f_hat stays 0)
        outs[0] = 7.5f * lacc[0] * (1.0f / (float)FELEMS);
        outs[1] = expf(-sh[0]);
    }
}

// ---------------------------------------------------------------------------
extern "C" void kernel_launch(void* const* d_in, const int* in_sizes, int n_in,
                              void* d_out, int out_size, void* d_ws, size_t ws_size,
                              hipStream_t stream) {
    const float* f   = (const float*)d_in[0];   // (32,32,32,32)
    const float* emb = (const float*)d_in[1];   // (4096,32)
    const float* phw = (const float*)d_in[2];   // (4,32,32,3,3)
    const float* phb = (const float*)d_in[3];   // (4,32)
    float* out = (float*)d_out;                 // f_hat (1048576) + loss + perplexity

    float* ws      = (float*)d_ws;
    float* hits    = ws;                              // [0, 4096)
    float* nesqh   = ws + 4096;                       // [4096, 8192)
    float* lacc    = ws + 8192;                       // [8192, 8448) padded
    u64_t* pkbase  = (u64_t*)(ws + 8448);             // 43680 u64 -> [8448, 95808)
    float* frest   = ws + 95808;                      // [95808, 1144384)
    ushort_t* zhi  = (ushort_t*)(ws + 1144384);       // 262144 us (si<=4 max N=8192)
    ushort_t* zmd  = (ushort_t*)(ws + 1275456);
    ushort_t* zlo  = (ushort_t*)(ws + 1406528);       // ends 1537600
    float* hup     = ws + 1537600;                    // [1537600, 2586176)
    ushort_t* ehi  = (ushort_t*)(ws + 2586176);       // 131072 us each
    ushort_t* emd  = (ushort_t*)(ws + 2651712);
    ushort_t* elo  = (ushort_t*)(ws + 2717248);       // ends 2782784 (11.1 MB)

    hipMemsetAsync(d_out, 0, (size_t)out_size * sizeof(float), stream);   // f_hat = 0
    hipMemsetAsync(ws, 0, (size_t)8448 * sizeof(float), stream);          // hits/lacc
    hipMemsetAsync(pkbase, 0xFF, (size_t)NROWS_TOTAL * 8, stream);        // pk = +inf key

    prep_kernel<<<VV / 256, 256, 0, stream>>>(emb, ehi, emd, elo, nesqh);

    const int pns[6]   = {1, 2, 4, 8, 16, 32};
    const int sel[6]   = {0, 0, 1, 2, 3, 3};            // PHI_SEL
    const int pkoff[6] = {0, 32, 160, 672, 2720, 10912};

    for (int si = 0; si < 6; si++) {
        int pn = pns[si];
        int N = BS * pn * pn;
        u64_t* pk = pkbase + pkoff[si];
        const float* srcf = (si == 0) ? f : frest;      // frest not yet written at si=0

        if (si == 5) {
            argmin5_fused<<<dim3(512, 4), 256, 0, stream>>>(frest, ehi, emd, elo, nesqh, pk);
        } else {
            if (pn <= 4) {
                if (si == 0)
                    pool_small_kernel<true><<<N, 256, 0, stream>>>(srcf, zhi, zmd, zlo, lacc, pn);
                else
                    pool_small_kernel<false><<<N, 256, 0, stream>>>(srcf, zhi, zmd, zlo, lacc, pn);
            } else {
                pool_kernel<<<(N * CH) / 256, 256, 0, stream>>>(srcf, zhi, zmd, zlo, pn);
            }
            if (si <= 2)        // N=32/128/512 -> grids 32/128/512
                argmin_stage<1, 16><<<dim3(N / 16, 16), 256, 0, stream>>>(zhi, zmd, zlo, ehi, emd, elo, nesqh, pk);
            else if (si == 3)   // N=2048 -> grid 1024
                argmin_stage<1, 8><<<dim3(N / 16, 8), 256, 0, stream>>>(zhi, zmd, zlo, ehi, emd, elo, nesqh, pk);
            else                // si=4, N=8192 -> grid 1024
                argmin_stage<2, 4><<<dim3(N / 32, 4), 256, 0, stream>>>(zhi, zmd, zlo, ehi, emd, elo, nesqh, pk);

            upsample_gather_kernel<<<FELEMS / 256, 256, 0, stream>>>(pk, emb, hup, pn);
            conv_phi_kernel<<<256, 256, 0, stream>>>(
                hup, phw + (size_t)sel[si] * CH * CH * 9,
                phb + (size_t)sel[si] * CH, srcf, frest);
        }
    }

    bincount_kernel<<<(NROWS_TOTAL + 255) / 256, 256, 0, stream>>>(pkbase, hits, NROWS_TOTAL);
    finalize_kernel<<<1, 256, 0, stream>>>(hits, lacc, out + (out_size - 2));
}